// Round 2
// baseline (1440.180 us; speedup 1.0000x reference)
//
#include <hip/hip_runtime.h>
#include <math.h>

#define N 1024
#define D 256
#define E 16
#define H 8
#define HD 32
#define F 1024
#define NN (1024 * 1024)
#define SCALE 0.17677669529663687f /* 1/sqrt(32) */
#define EPS 1e-6f

// ---------------- block reduction helpers (256-thread blocks) ----------------
__device__ __forceinline__ float block_sum(float v) {
    #pragma unroll
    for (int off = 32; off > 0; off >>= 1) v += __shfl_xor(v, off);
    __shared__ float ws[4];
    if ((threadIdx.x & 63) == 0) ws[threadIdx.x >> 6] = v;
    __syncthreads();
    v = ws[0] + ws[1] + ws[2] + ws[3];
    __syncthreads();
    return v;
}

__device__ __forceinline__ float block_max(float v) {
    #pragma unroll
    for (int off = 32; off > 0; off >>= 1) v = fmaxf(v, __shfl_xor(v, off));
    __shared__ float wm[4];
    if ((threadIdx.x & 63) == 0) wm[threadIdx.x >> 6] = v;
    __syncthreads();
    v = fmaxf(fmaxf(wm[0], wm[1]), fmaxf(wm[2], wm[3]));
    __syncthreads();
    return v;
}

__device__ __forceinline__ float silu_f(float x) { return x / (1.f + expf(-x)); }
__device__ __forceinline__ float sigmoid_f(float x) { return 1.f / (1.f + expf(-x)); }

// ---------------- elementwise ----------------
__global__ void copy4_kernel(const float4* __restrict__ a, float4* __restrict__ b, int n4) {
    int i = blockIdx.x * 256 + threadIdx.x;
    if (i < n4) b[i] = a[i];
}

__global__ void mul_kernel(float* __restrict__ a, const float* __restrict__ b, int n) {
    int i = blockIdx.x * 256 + threadIdx.x;
    if (i < n) a[i] *= b[i];
}

// x += sigmoid(g) * t
__global__ void gate_combine_kernel(const float* __restrict__ g, const float* __restrict__ t,
                                    float* __restrict__ x, int n) {
    int i = blockIdx.x * 256 + threadIdx.x;
    if (i < n) x[i] += sigmoid_f(g[i]) * t[i];
}

// ---------------- rmsnorm: one block per row, D=256 ----------------
__global__ void rmsnorm_kernel(const float* __restrict__ x, const float* __restrict__ w,
                               float* __restrict__ out) {
    int row = blockIdx.x;
    int t = threadIdx.x;
    float v = x[(long)row * D + t];
    float s = block_sum(v * v);
    float rms = sqrtf(s * (1.f / D) + EPS);
    out[(long)row * D + t] = v / rms * w[t];
}

// ---------------- generic fp32 GEMM: C[M,Nc] (+)= act(A[M,K] @ B[K,Nc] + bias) ----------
// 64x64 tile, 256 threads, 4x4 per thread, K-tile 16, float4 global loads.
// Batched via gridDim.z + strides. M, Nc multiples of 4 assumed for float4 guards.
template <int ACT, bool ACCUM, bool BIAS>
__global__ void gemm_kernel(const float* __restrict__ A, const float* __restrict__ B,
                            const float* __restrict__ bias, float* __restrict__ C,
                            int M, int K, int Nc, int lda, int ldb, int ldc,
                            long sA, long sB, long sC) {
    int batch = blockIdx.z;
    A += (long)batch * sA;
    B += (long)batch * sB;
    C += (long)batch * sC;
    __shared__ float As[16][68]; // As[k][m], stride 68 keeps float4 alignment, <=2-way banks
    __shared__ float Bs[16][68]; // Bs[k][n]
    int m0 = blockIdx.y * 64, n0 = blockIdx.x * 64;
    int t = threadIdx.x;
    int tm = t >> 4, tn = t & 15;
    int am = t >> 2, ak = (t & 3) * 4;   // A loader: one float4 along k
    int bk = t >> 4, bn = (t & 15) * 4;  // B loader: one float4 along n
    float acc[4][4] = {};
    for (int k0 = 0; k0 < K; k0 += 16) {
        float4 av = make_float4(0.f, 0.f, 0.f, 0.f);
        int gm = m0 + am;
        if (gm < M) av = *(const float4*)&A[(long)gm * lda + k0 + ak];
        As[ak + 0][am] = av.x;
        As[ak + 1][am] = av.y;
        As[ak + 2][am] = av.z;
        As[ak + 3][am] = av.w;
        float4 bv = make_float4(0.f, 0.f, 0.f, 0.f);
        int gn = n0 + bn;
        if (gn < Nc) bv = *(const float4*)&B[(long)(k0 + bk) * ldb + gn];
        *(float4*)&Bs[bk][bn] = bv;
        __syncthreads();
        #pragma unroll
        for (int k = 0; k < 16; k++) {
            float4 a4 = *(const float4*)&As[k][tm * 4];
            float4 b4 = *(const float4*)&Bs[k][tn * 4];
            float a[4] = {a4.x, a4.y, a4.z, a4.w};
            float b[4] = {b4.x, b4.y, b4.z, b4.w};
            #pragma unroll
            for (int i = 0; i < 4; i++)
                #pragma unroll
                for (int j = 0; j < 4; j++) acc[i][j] += a[i] * b[j];
        }
        __syncthreads();
    }
    #pragma unroll
    for (int i = 0; i < 4; i++) {
        int gm = m0 + tm * 4 + i;
        if (gm >= M) continue;
        #pragma unroll
        for (int j = 0; j < 4; j++) {
            int gn = n0 + tn * 4 + j;
            if (gn >= Nc) continue;
            float v = acc[i][j];
            if (BIAS) v += bias[gn];
            if (ACT == 1) v = silu_f(v);
            long off = (long)gm * ldc + gn;
            if (ACCUM)
                C[off] += v;
            else
                C[off] = v;
        }
    }
}

// ---------------- scores: s[h,i,j] = scale*dot(q_h[i],k_h[j]) (+bias) (mask) -----------
// MASK: 0 none, 1 role, 2 neighbor
template <int MASK, bool BIASED>
__global__ void scores_kernel(const float* __restrict__ q, const float* __restrict__ k,
                              const float* __restrict__ ebias,
                              const int* __restrict__ roles,
                              const int* __restrict__ adj, float* __restrict__ s) {
    int h = blockIdx.z, i0 = blockIdx.y * 64, j0 = blockIdx.x * 64;
    __shared__ float Qs[64][33], Ks[64][33];
    int t = threadIdx.x;
    #pragma unroll
    for (int r = 0; r < 8; r++) {
        int idx = t + r * 256;
        int row = idx >> 5, col = idx & 31;
        Qs[row][col] = q[(long)(i0 + row) * D + h * HD + col];
        Ks[row][col] = k[(long)(j0 + row) * D + h * HD + col];
    }
    __syncthreads();
    int ti = t >> 4, tj = t & 15;
    float acc[4][4] = {};
    #pragma unroll
    for (int kk = 0; kk < HD; kk++) {
        float a[4], b[4];
        #pragma unroll
        for (int x = 0; x < 4; x++) a[x] = Qs[ti * 4 + x][kk];
        #pragma unroll
        for (int y = 0; y < 4; y++) b[y] = Ks[tj * 4 + y][kk];
        #pragma unroll
        for (int x = 0; x < 4; x++)
            #pragma unroll
            for (int y = 0; y < 4; y++) acc[x][y] += a[x] * b[y];
    }
    #pragma unroll
    for (int x = 0; x < 4; x++) {
        int i = i0 + ti * 4 + x;
        int ri = 0;
        if (MASK == 1) ri = roles[i];
        #pragma unroll
        for (int y = 0; y < 4; y++) {
            int j = j0 + tj * 4 + y;
            float val = acc[x][y] * SCALE;
            if (BIASED) val += ebias[((long)i * N + j) * H + h];
            if (MASK == 1) {
                if (roles[j] != ri) val = -1e30f;
            } else if (MASK == 2) {
                if (!(adj[(long)i * N + j] > 0 || i == j)) val = -1e30f;
            }
            s[(long)h * NN + (long)i * N + j] = val;
        }
    }
}

// ---------------- softmax over last dim (1024), one block per (h,i) row --------------
__global__ void softmax_kernel(float* __restrict__ s) {
    long base = (long)blockIdx.x << 10;
    int t = threadIdx.x;
    float v[4];
    #pragma unroll
    for (int r = 0; r < 4; r++) v[r] = s[base + t + r * 256];
    float m = fmaxf(fmaxf(v[0], v[1]), fmaxf(v[2], v[3]));
    m = block_max(m);
    float sum = 0.f;
    #pragma unroll
    for (int r = 0; r < 4; r++) {
        v[r] = expf(v[r] - m);
        sum += v[r];
    }
    sum = block_sum(sum);
    float inv = 1.f / sum;
    #pragma unroll
    for (int r = 0; r < 4; r++) s[base + t + r * 256] = v[r] * inv;
}

// ---------------- fused edge MLP: ebias[i,j,h] = silu(ef[i,j,:]@w1+b1)@w2+b2 ----------
// one block per i; 32-j tiles. w1 column lives in registers (16 VGPR/thread).
// pass2 partitions (jl = t&31, d-slice = t>>5); partials reduced through LDS.
__global__ void edge_mlp_kernel(const float* __restrict__ ef, const float* __restrict__ w1,
                                const float* __restrict__ b1, const float* __restrict__ w2,
                                const float* __restrict__ b2, float* __restrict__ ebias) {
    __shared__ float w2s[D * H];         // 8 KB, row d = 8 consecutive floats (16B-aligned)
    __shared__ float efs[32 * E];        // 2 KB, 32 contiguous rows of ef
    __shared__ float hdn[32][D + 1];     // stride 257: scalar reads 2-way max (free)
    __shared__ float part[8][32 * 9];    // [d-slice][jl*9 + h], pad 9 kills conflicts
    int t = threadIdx.x;
    int i = blockIdx.x;
    float w1r[E];
    #pragma unroll
    for (int e = 0; e < E; e++) w1r[e] = w1[e * D + t];  // coalesced, once
    float b1r = b1[t];
    #pragma unroll
    for (int r = 0; r < 8; r++) w2s[t + r * 256] = w2[t + r * 256];
    int jl2 = t & 31, ds = t >> 5;       // pass-2 ownership
    int jlo = t >> 3, ho = t & 7;        // reduction/output ownership
    float b2r = b2[ho];
    __syncthreads();
    for (int j0 = 0; j0 < N; j0 += 32) {
        // stage 32 contiguous ef rows (512 floats) as float4
        if (t < 128) {
            *(float4*)&efs[t * 4] = *(const float4*)&ef[((long)i * N + j0) * E + t * 4];
        }
        __syncthreads();
        // pass 1: thread t owns hidden dim d=t for all 32 j's (efs reads broadcast)
        for (int jl = 0; jl < 32; jl++) {
            float acc = b1r;
            #pragma unroll
            for (int e = 0; e < E; e++) acc += efs[jl * E + e] * w1r[e];
            hdn[jl][t] = silu_f(acc);
        }
        __syncthreads();
        // pass 2: 8 h-accumulators over 32-wide d slice
        float acc[8] = {0.f, 0.f, 0.f, 0.f, 0.f, 0.f, 0.f, 0.f};
        #pragma unroll 8
        for (int dd = 0; dd < 32; dd++) {
            int d = ds * 32 + dd;
            float hv = hdn[jl2][d];
            float4 wa = *(const float4*)&w2s[d * 8];
            float4 wb = *(const float4*)&w2s[d * 8 + 4];
            acc[0] += hv * wa.x; acc[1] += hv * wa.y;
            acc[2] += hv * wa.z; acc[3] += hv * wa.w;
            acc[4] += hv * wb.x; acc[5] += hv * wb.y;
            acc[6] += hv * wb.z; acc[7] += hv * wb.w;
        }
        {
            float* p = &part[ds][jl2 * 9];
            #pragma unroll
            for (int h = 0; h < 8; h++) p[h] = acc[h];
        }
        __syncthreads();
        float sacc = b2r;
        #pragma unroll
        for (int d2 = 0; d2 < 8; d2++) sacc += part[d2][jlo * 9 + ho];
        ebias[((long)i * N + j0 + jlo) * H + ho] = sacc;
        __syncthreads();
    }
}

// =====================================================================================
extern "C" void kernel_launch(void* const* d_in, const int* in_sizes, int n_in,
                              void* d_out, int out_size, void* d_ws, size_t ws_size,
                              hipStream_t stream) {
    const float* features   = (const float*)d_in[0];
    const int*   adjacency  = (const int*)d_in[1];
    const float* edge_feats = (const float*)d_in[2];
    const int*   role_idx   = (const int*)d_in[3];
    const float* role_norm_w = (const float*)d_in[4];
    const float* role_q_w = (const float*)d_in[5];
    const float* role_k_w = (const float*)d_in[6];
    const float* role_v_w = (const float*)d_in[7];
    const float* role_o_w = (const float*)d_in[8];
    const float* nb_norm_w = (const float*)d_in[9];
    const float* nb_q_w = (const float*)d_in[10];
    const float* nb_k_w = (const float*)d_in[11];
    const float* nb_v_w = (const float*)d_in[12];
    const float* nb_o_w = (const float*)d_in[13];
    const float* edge_w1 = (const float*)d_in[14];
    const float* edge_b1 = (const float*)d_in[15];
    const float* edge_w2 = (const float*)d_in[16];
    const float* edge_b2 = (const float*)d_in[17];
    const float* full_norm_w = (const float*)d_in[18];
    const float* full_q_w = (const float*)d_in[19];
    const float* full_k_w = (const float*)d_in[20];
    const float* full_v_w = (const float*)d_in[21];
    const float* full_o_w = (const float*)d_in[22];
    const float* feat_norm_w = (const float*)d_in[23];
    const float* feat_t_w = (const float*)d_in[24];
    const float* feat_t_b = (const float*)d_in[25];
    const float* feat_g_w = (const float*)d_in[26];
    const float* feat_g_b = (const float*)d_in[27];
    const float* ffn_norm_w = (const float*)d_in[28];
    const float* ffn_gate_w = (const float*)d_in[29];
    const float* ffn_up_w = (const float*)d_in[30];
    const float* ffn_down_w = (const float*)d_in[31];

    float* ws = (float*)d_ws;
    float* x   = ws;                       // N*D
    float* xn  = x + (size_t)N * D;
    float* qb  = xn + (size_t)N * D;
    float* kb  = qb + (size_t)N * D;
    float* vb  = kb + (size_t)N * D;
    float* ao  = vb + (size_t)N * D;       // attn out / t buffer
    float* tmp = ao + (size_t)N * D;       // gate pre-activation
    float* sc  = tmp + (size_t)N * D;      // H*N*N scores
    float* eb  = sc + (size_t)H * NN;      // N*N*H edge bias
    float* gb  = eb + (size_t)N * H * N;   // N*F
    float* ub  = gb + (size_t)N * F;       // N*F

    auto gemm = [&](const float* A, const float* B, const float* bias, float* C,
                    int M, int K, int Nc, int lda, int ldb, int ldc,
                    long sA, long sB, long sC, int batch, int act, bool accum) {
        dim3 grid((Nc + 63) / 64, (M + 63) / 64, batch);
        dim3 blk(256);
        if (act == 0 && !accum && bias == nullptr)
            gemm_kernel<0, false, false><<<grid, blk, 0, stream>>>(A, B, bias, C, M, K, Nc, lda, ldb, ldc, sA, sB, sC);
        else if (act == 0 && accum && bias == nullptr)
            gemm_kernel<0, true, false><<<grid, blk, 0, stream>>>(A, B, bias, C, M, K, Nc, lda, ldb, ldc, sA, sB, sC);
        else if (act == 0 && !accum && bias != nullptr)
            gemm_kernel<0, false, true><<<grid, blk, 0, stream>>>(A, B, bias, C, M, K, Nc, lda, ldb, ldc, sA, sB, sC);
        else if (act == 1 && !accum && bias != nullptr)
            gemm_kernel<1, false, true><<<grid, blk, 0, stream>>>(A, B, bias, C, M, K, Nc, lda, ldb, ldc, sA, sB, sC);
        else /* act==1, !accum, no bias */
            gemm_kernel<1, false, false><<<grid, blk, 0, stream>>>(A, B, bias, C, M, K, Nc, lda, ldb, ldc, sA, sB, sC);
    };

    // x = features
    copy4_kernel<<<(N * D / 4) / 256, 256, 0, stream>>>((const float4*)features, (float4*)x, N * D / 4);
    // edge bias (independent of x; run up front)
    edge_mlp_kernel<<<N, 256, 0, stream>>>(edge_feats, edge_w1, edge_b1, edge_w2, edge_b2, eb);

    dim3 sgrid(16, 16, 8);

    // ---- 1. role attention ----
    rmsnorm_kernel<<<N, 256, 0, stream>>>(x, role_norm_w, xn);
    gemm(xn, role_q_w, nullptr, qb, N, D, D, D, D, D, 0, 0, 0, 1, 0, false);
    gemm(xn, role_k_w, nullptr, kb, N, D, D, D, D, D, 0, 0, 0, 1, 0, false);
    gemm(xn, role_v_w, nullptr, vb, N, D, D, D, D, D, 0, 0, 0, 1, 0, false);
    scores_kernel<1, false><<<sgrid, 256, 0, stream>>>(qb, kb, nullptr, role_idx, nullptr, sc);
    softmax_kernel<<<H * N, 256, 0, stream>>>(sc);
    gemm(sc, vb, nullptr, ao, N, N, HD, N, D, D, (long)NN, HD, HD, H, 0, false);
    gemm(ao, role_o_w, nullptr, x, N, D, D, D, D, D, 0, 0, 0, 1, 0, true);

    // ---- 2. neighbor attention (with edge bias) ----
    rmsnorm_kernel<<<N, 256, 0, stream>>>(x, nb_norm_w, xn);
    gemm(xn, nb_q_w, nullptr, qb, N, D, D, D, D, D, 0, 0, 0, 1, 0, false);
    gemm(xn, nb_k_w, nullptr, kb, N, D, D, D, D, D, 0, 0, 0, 1, 0, false);
    gemm(xn, nb_v_w, nullptr, vb, N, D, D, D, D, D, 0, 0, 0, 1, 0, false);
    scores_kernel<2, true><<<sgrid, 256, 0, stream>>>(qb, kb, eb, nullptr, adjacency, sc);
    softmax_kernel<<<H * N, 256, 0, stream>>>(sc);
    gemm(sc, vb, nullptr, ao, N, N, HD, N, D, D, (long)NN, HD, HD, H, 0, false);
    gemm(ao, nb_o_w, nullptr, x, N, D, D, D, D, D, 0, 0, 0, 1, 0, true);

    // ---- 3. full attention ----
    rmsnorm_kernel<<<N, 256, 0, stream>>>(x, full_norm_w, xn);
    gemm(xn, full_q_w, nullptr, qb, N, D, D, D, D, D, 0, 0, 0, 1, 0, false);
    gemm(xn, full_k_w, nullptr, kb, N, D, D, D, D, D, 0, 0, 0, 1, 0, false);
    gemm(xn, full_v_w, nullptr, vb, N, D, D, D, D, D, 0, 0, 0, 1, 0, false);
    scores_kernel<0, false><<<sgrid, 256, 0, stream>>>(qb, kb, nullptr, nullptr, nullptr, sc);
    softmax_kernel<<<H * N, 256, 0, stream>>>(sc);
    gemm(sc, vb, nullptr, ao, N, N, HD, N, D, D, (long)NN, HD, HD, H, 0, false);
    gemm(ao, full_o_w, nullptr, x, N, D, D, D, D, D, 0, 0, 0, 1, 0, true);

    // ---- 4. feature mixing ----
    rmsnorm_kernel<<<N, 256, 0, stream>>>(x, feat_norm_w, xn);
    gemm(xn, feat_t_w, feat_t_b, ao, N, D, D, D, D, D, 0, 0, 0, 1, 1, false);      // t = silu(xn@Wt+b)
    gemm(xn, feat_g_w, feat_g_b, tmp, N, D, D, D, D, D, 0, 0, 0, 1, 0, false);     // tmp = xn@G1+b
    gemm(ao, feat_g_w + (size_t)D * D, nullptr, tmp, N, D, D, D, D, D, 0, 0, 0, 1, 0, true); // tmp += t@G2
    gate_combine_kernel<<<(N * D) / 256, 256, 0, stream>>>(tmp, ao, x, N * D);

    // ---- 5. gated FFN ----
    rmsnorm_kernel<<<N, 256, 0, stream>>>(x, ffn_norm_w, xn);
    gemm(xn, ffn_gate_w, nullptr, gb, N, D, F, D, F, F, 0, 0, 0, 1, 1, false);     // silu(xn@Wg)
    gemm(xn, ffn_up_w, nullptr, ub, N, D, F, D, F, F, 0, 0, 0, 1, 0, false);
    mul_kernel<<<(N * F) / 256, 256, 0, stream>>>(gb, ub, N * F);
    gemm(gb, ffn_down_w, nullptr, x, N, F, D, F, D, D, 0, 0, 0, 1, 0, true);

    copy4_kernel<<<(N * D / 4) / 256, 256, 0, stream>>>((const float4*)x, (float4*)d_out, N * D / 4);
}

// Round 6
// 685.839 us; speedup vs baseline: 2.0999x; 2.0999x over previous
//
#include <hip/hip_runtime.h>
#include <math.h>

#define N 1024
#define D 256
#define E 16
#define H 8
#define HD 32
#define F 1024
#define NN (1024 * 1024)
#define SCALE 0.17677669529663687f /* 1/sqrt(32) */
#define EPS 1e-6f

typedef unsigned short u16;
typedef __attribute__((ext_vector_type(8))) short bfrag8;
typedef __attribute__((ext_vector_type(4))) float accf4;

// ---------------- helpers ----------------
__device__ __forceinline__ float block_sum(float v) {
    #pragma unroll
    for (int off = 32; off > 0; off >>= 1) v += __shfl_xor(v, off);
    __shared__ float ws[4];
    if ((threadIdx.x & 63) == 0) ws[threadIdx.x >> 6] = v;
    __syncthreads();
    v = ws[0] + ws[1] + ws[2] + ws[3];
    __syncthreads();
    return v;
}

__device__ __forceinline__ float block_max(float v) {
    #pragma unroll
    for (int off = 32; off > 0; off >>= 1) v = fmaxf(v, __shfl_xor(v, off));
    __shared__ float wm[4];
    if ((threadIdx.x & 63) == 0) wm[threadIdx.x >> 6] = v;
    __syncthreads();
    v = fmaxf(fmaxf(wm[0], wm[1]), fmaxf(wm[2], wm[3]));
    __syncthreads();
    return v;
}

__device__ __forceinline__ float silu_f(float x) { return x / (1.f + expf(-x)); }
__device__ __forceinline__ float sigmoid_f(float x) { return 1.f / (1.f + expf(-x)); }

__device__ __forceinline__ u16 f2bf(float x) {
    union { float f; unsigned int u; } c;
    c.f = x;
    unsigned int r = c.u + 0x7fffu + ((c.u >> 16) & 1u);
    return (u16)(r >> 16);
}

__device__ __forceinline__ unsigned int cvt_pk_bf16(float a, float b) {
    unsigned int r;
    asm("v_cvt_pk_bf16_f32 %0, %1, %2" : "=v"(r) : "v"(a), "v"(b));
    return r;
}

// ---------------- elementwise ----------------
__global__ void copy4_kernel(const float4* __restrict__ a, float4* __restrict__ b, int n4) {
    int i = blockIdx.x * 256 + threadIdx.x;
    if (i < n4) b[i] = a[i];
}

// x += sigmoid(g) * t
__global__ void gate_combine_kernel(const float* __restrict__ g, const float* __restrict__ t,
                                    float* __restrict__ x, int n) {
    int i = blockIdx.x * 256 + threadIdx.x;
    if (i < n) x[i] += sigmoid_f(g[i]) * t[i];
}

__global__ void cvt_bf16_kernel(const float* __restrict__ in, u16* __restrict__ out, int n) {
    int i = blockIdx.x * 256 + threadIdx.x;
    if (i < n) out[i] = f2bf(in[i]);
}

// hb[j,f] = bf16( silu(guv[j,f]) * guv[j,F+f] )
__global__ void ffn_mulcvt_kernel(const float* __restrict__ guv, u16* __restrict__ hb) {
    int i = blockIdx.x * 256 + threadIdx.x;
    int j = i >> 10, f = i & 1023;
    float g = guv[(long)j * 2048 + f];
    float u = guv[(long)j * 2048 + 1024 + f];
    hb[i] = f2bf(silu_f(g) * u);
}

// ---------------- rmsnorm -> bf16: one block per row, D=256 ----------------
__global__ void rmsnorm_bf16_kernel(const float* __restrict__ x, const float* __restrict__ w,
                                    u16* __restrict__ out) {
    int row = blockIdx.x;
    int t = threadIdx.x;
    float v = x[(long)row * D + t];
    float s = block_sum(v * v);
    float rms = sqrtf(s * (1.f / D) + EPS);
    out[(long)row * D + t] = f2bf(v / rms * w[t]);
}

// ---------------- transpose+convert: in fp32 [K][ldin] block -> out bf16 [Nc][K] ------
__global__ void transpose_bf16_kernel(const float* __restrict__ in, long ldin,
                                      u16* __restrict__ out, int K, int Nc) {
    __shared__ float tile[32][33];
    int k0 = blockIdx.y * 32, n0 = blockIdx.x * 32;
    int c = threadIdx.x & 31, r8 = threadIdx.x >> 5;
    #pragma unroll
    for (int i = 0; i < 4; i++) {
        int r = r8 + i * 8;
        tile[r][c] = in[(long)(k0 + r) * ldin + n0 + c];
    }
    __syncthreads();
    #pragma unroll
    for (int i = 0; i < 4; i++) {
        int r = r8 + i * 8;
        out[(long)(n0 + r) * K + k0 + c] = f2bf(tile[c][r]);
    }
}

// ---------------- bf16 MFMA GEMM ----------------
// C[M][ldc] (+)= act(A[M][K] @ B^T[Nc][K] + bias); A,B bf16 row-major (B pre-transposed).
// Block: 256 thr = 4 waves; tile 64 x NTILE (NTILE = NTW*16); wave w owns rows w*16..w*16+15.
// LDS rows padded to 72 u16 (144 B) -> all ds accesses at the 8-cycle floor (no conflicts).
// A-frag: row = lane&15, k = (lane>>4)*8+j.  C: row=(lane>>4)*4+reg, col=lane&15 (m89).
template <int NTW, int ACT, bool ACCUM, bool BIAS, bool BF16O>
__global__ __launch_bounds__(256) void bgemm_kernel(
    const u16* __restrict__ A, const u16* __restrict__ B, const float* __restrict__ bias,
    void* __restrict__ C, int M, int K, int Nc, int ldc, long sA, long sB, long sC) {
    constexpr int NTILE = NTW * 16;
    __shared__ __align__(16) u16 Asm[64 * 72];
    __shared__ __align__(16) u16 Bsm[NTILE * 72];
    A += (long)blockIdx.z * sA;
    B += (long)blockIdx.z * sB;
    long cbase = (long)blockIdx.z * sC;
    int m0 = blockIdx.y * 64, n0 = blockIdx.x * NTILE;
    int t = threadIdx.x;
    int wave = t >> 6, lane = t & 63, lg = lane >> 4, lr = lane & 15;
    accf4 acc[NTW] = {};
    for (int k0 = 0; k0 < K; k0 += 64) {
        #pragma unroll
        for (int c = 0; c < 2; c++) {
            int flat = c * 4096 + t * 16;
            int row = flat >> 7, col = (flat & 127) >> 1;
            *(int4*)&Asm[row * 72 + col] = *(const int4*)&A[(long)(m0 + row) * K + k0 + col];
        }
        #pragma unroll
        for (int c = 0; c < NTW / 2; c++) {
            int flat = c * 4096 + t * 16;
            int row = flat >> 7, col = (flat & 127) >> 1;
            *(int4*)&Bsm[row * 72 + col] = *(const int4*)&B[(long)(n0 + row) * K + k0 + col];
        }
        __syncthreads();
        #pragma unroll
        for (int ks = 0; ks < 2; ks++) {
            bfrag8 af = *(const bfrag8*)&Asm[(wave * 16 + lr) * 72 + ks * 32 + lg * 8];
            #pragma unroll
            for (int nt = 0; nt < NTW; nt++) {
                bfrag8 bf = *(const bfrag8*)&Bsm[(nt * 16 + lr) * 72 + ks * 32 + lg * 8];
                acc[nt] = __builtin_amdgcn_mfma_f32_16x16x32_bf16(af, bf, acc[nt], 0, 0, 0);
            }
        }
        __syncthreads();
    }
    float* Cf = (float*)C;
    u16* Cb = (u16*)C;
    #pragma unroll
    for (int nt = 0; nt < NTW; nt++) {
        int gn = n0 + nt * 16 + lr;
        #pragma unroll
        for (int r = 0; r < 4; r++) {
            int gm = m0 + wave * 16 + lg * 4 + r;
            float v = acc[nt][r];
            if (BIAS) v += bias[gn];
            if (ACT == 1) v = silu_f(v);
            long idx = cbase + (long)gm * ldc + gn;
            if (BF16O) Cb[idx] = f2bf(v);
            else if (ACCUM) Cf[idx] += v;
            else Cf[idx] = v;
        }
    }
}

// ---------------- scores: fp32 (q,k from fused qkv buffer, row stride ldq) -------------
template <int MASK, bool BIASED>
__global__ void scores_kernel(const float* __restrict__ q, const float* __restrict__ k, int ldq,
                              const float* __restrict__ ebias,
                              const int* __restrict__ roles,
                              const int* __restrict__ adj, float* __restrict__ s) {
    int h = blockIdx.z, i0 = blockIdx.y * 64, j0 = blockIdx.x * 64;
    __shared__ float Qs[64][33], Ks[64][33];
    int t = threadIdx.x;
    #pragma unroll
    for (int r = 0; r < 8; r++) {
        int idx = t + r * 256;
        int row = idx >> 5, col = idx & 31;
        Qs[row][col] = q[(long)(i0 + row) * ldq + h * HD + col];
        Ks[row][col] = k[(long)(j0 + row) * ldq + h * HD + col];
    }
    __syncthreads();
    int ti = t >> 4, tj = t & 15;
    float acc[4][4] = {};
    #pragma unroll
    for (int kk = 0; kk < HD; kk++) {
        float a[4], b[4];
        #pragma unroll
        for (int x = 0; x < 4; x++) a[x] = Qs[ti * 4 + x][kk];
        #pragma unroll
        for (int y = 0; y < 4; y++) b[y] = Ks[tj * 4 + y][kk];
        #pragma unroll
        for (int x = 0; x < 4; x++)
            #pragma unroll
            for (int y = 0; y < 4; y++) acc[x][y] += a[x] * b[y];
    }
    #pragma unroll
    for (int x = 0; x < 4; x++) {
        int i = i0 + ti * 4 + x;
        int ri = 0;
        if (MASK == 1) ri = roles[i];
        #pragma unroll
        for (int y = 0; y < 4; y++) {
            int j = j0 + tj * 4 + y;
            float val = acc[x][y] * SCALE;
            if (BIASED) val += ebias[((long)i * N + j) * H + h];
            if (MASK == 1) {
                if (roles[j] != ri) val = -1e30f;
            } else if (MASK == 2) {
                if (!(adj[(long)i * N + j] > 0 || i == j)) val = -1e30f;
            }
            s[(long)h * NN + (long)i * N + j] = val;
        }
    }
}

// ---------------- softmax over last dim (1024): read fp32, write bf16 probs -----------
__global__ void softmax_kernel(const float* __restrict__ s, u16* __restrict__ sb) {
    long base = (long)blockIdx.x << 10;
    int t = threadIdx.x;
    float v[4];
    #pragma unroll
    for (int r = 0; r < 4; r++) v[r] = s[base + t + r * 256];
    float m = fmaxf(fmaxf(v[0], v[1]), fmaxf(v[2], v[3]));
    m = block_max(m);
    float sum = 0.f;
    #pragma unroll
    for (int r = 0; r < 4; r++) {
        v[r] = expf(v[r] - m);
        sum += v[r];
    }
    sum = block_sum(sum);
    float inv = 1.f / sum;
    #pragma unroll
    for (int r = 0; r < 4; r++) sb[base + t + r * 256] = f2bf(v[r] * inv);
}

// ---------------- edge MLP via MFMA bf16 ----------------
// MM1 (operand-swapped): D1[d_loc][r] = W1^T-tile * EF^T-tile, bias folded at k=16.
// C-layout (m89): row=(lane>>4)*4+reg, col=lane&15 -> lane owns col r=lane&15 and 4
// CONSECUTIVE d per tile -> single 8B write of packed bf16 hidden. MM2 reads it back
// as 16B ds_read_b128. Per-wave private hidden buffer -> no barriers in main loop.
__global__ __launch_bounds__(256, 3) void edge_mlp_mfma_kernel(
    const float* __restrict__ ef, const float* __restrict__ w1, const float* __restrict__ b1,
    const float* __restrict__ w2, const float* __restrict__ b2, float* __restrict__ ebias) {
    __shared__ __align__(16) u16 w1t[256 * 16];
    __shared__ __align__(16) u16 w2t[16 * 256];
    __shared__ __align__(16) u16 hid[4][16 * 264];
    int t = threadIdx.x;
    int i = blockIdx.x;

    {
        int d = t;
        #pragma unroll
        for (int e = 0; e < 16; e++) w1t[d * 16 + e] = f2bf(w1[e * 256 + d]);
        float4 wa = *(const float4*)&w2[d * 8];
        float4 wb = *(const float4*)&w2[d * 8 + 4];
        w2t[0 * 256 + d] = f2bf(wa.x);
        w2t[1 * 256 + d] = f2bf(wa.y);
        w2t[2 * 256 + d] = f2bf(wa.z);
        w2t[3 * 256 + d] = f2bf(wa.w);
        w2t[4 * 256 + d] = f2bf(wb.x);
        w2t[5 * 256 + d] = f2bf(wb.y);
        w2t[6 * 256 + d] = f2bf(wb.z);
        w2t[7 * 256 + d] = f2bf(wb.w);
        #pragma unroll
        for (int h = 8; h < 16; h++) w2t[h * 256 + d] = 0;
    }
    __syncthreads();

    int wave = t >> 6, lane = t & 63;
    int lg = lane >> 4, lr = lane & 15;
    u16* hw = hid[wave];

    bfrag8 a1[16];
    #pragma unroll
    for (int dt = 0; dt < 16; dt++) {
        int d = dt * 16 + lr;
        if (lg < 2) {
            a1[dt] = *(const bfrag8*)&w1t[d * 16 + lg * 8];
        } else if (lg == 2) {
            union { unsigned int u[4]; bfrag8 s; } z = {{0u, 0u, 0u, 0u}};
            z.u[0] = (unsigned int)f2bf(b1[d]);
            a1[dt] = z.s;
        } else {
            union { unsigned int u[4]; bfrag8 s; } z = {{0u, 0u, 0u, 0u}};
            a1[dt] = z.s;
        }
    }
    bfrag8 a2[8];
    #pragma unroll
    for (int ks = 0; ks < 8; ks++)
        a2[ks] = *(const bfrag8*)&w2t[lr * 256 + ks * 32 + lg * 8];

    float b2v[4];
    #pragma unroll
    for (int r = 0; r < 4; r++) b2v[r] = (lg < 2) ? b2[lg * 4 + r] : 0.f;

    for (int it = 0; it < 16; it++) {
        long rowbase = (long)i * N + (it * 4 + wave) * 16;
        bfrag8 bfrag;
        if (lg < 2) {
            const float* p = &ef[(rowbase + lr) * E + lg * 8];
            float4 f0 = *(const float4*)p;
            float4 f1 = *(const float4*)(p + 4);
            union { unsigned int u[4]; bfrag8 s; } uu;
            uu.u[0] = cvt_pk_bf16(f0.x, f0.y);
            uu.u[1] = cvt_pk_bf16(f0.z, f0.w);
            uu.u[2] = cvt_pk_bf16(f1.x, f1.y);
            uu.u[3] = cvt_pk_bf16(f1.z, f1.w);
            bfrag = uu.s;
        } else {
            union { unsigned int u[4]; bfrag8 s; } uu = {{(lg == 2) ? 0x3f80u : 0u, 0u, 0u, 0u}};
            bfrag = uu.s;
        }
        #pragma unroll
        for (int dt = 0; dt < 16; dt++) {
            accf4 acc = {0.f, 0.f, 0.f, 0.f};
            acc = __builtin_amdgcn_mfma_f32_16x16x32_bf16(a1[dt], bfrag, acc, 0, 0, 0);
            float s0 = silu_f(acc[0]);
            float s1 = silu_f(acc[1]);
            float s2 = silu_f(acc[2]);
            float s3 = silu_f(acc[3]);
            uint2 pk;
            pk.x = cvt_pk_bf16(s0, s1);
            pk.y = cvt_pk_bf16(s2, s3);
            *(uint2*)&hw[lr * 264 + dt * 16 + lg * 4] = pk;
        }
        accf4 acc2 = {0.f, 0.f, 0.f, 0.f};
        #pragma unroll
        for (int ks = 0; ks < 8; ks++) {
            bfrag8 hb = *(const bfrag8*)&hw[lr * 264 + ks * 32 + lg * 8];
            acc2 = __builtin_amdgcn_mfma_f32_16x16x32_bf16(a2[ks], hb, acc2, 0, 0, 0);
        }
        if (lg < 2) {
            float* o = &ebias[(rowbase + lr) * H + lg * 4];
            #pragma unroll
            for (int r = 0; r < 4; r++) o[r] = acc2[r] + b2v[r];
        }
    }
}

// =====================================================================================
extern "C" void kernel_launch(void* const* d_in, const int* in_sizes, int n_in,
                              void* d_out, int out_size, void* d_ws, size_t ws_size,
                              hipStream_t stream) {
    const float* features   = (const float*)d_in[0];
    const int*   adjacency  = (const int*)d_in[1];
    const float* edge_feats = (const float*)d_in[2];
    const int*   role_idx   = (const int*)d_in[3];
    const float* role_norm_w = (const float*)d_in[4];
    const float* role_q_w = (const float*)d_in[5];
    const float* role_k_w = (const float*)d_in[6];
    const float* role_v_w = (const float*)d_in[7];
    const float* role_o_w = (const float*)d_in[8];
    const float* nb_norm_w = (const float*)d_in[9];
    const float* nb_q_w = (const float*)d_in[10];
    const float* nb_k_w = (const float*)d_in[11];
    const float* nb_v_w = (const float*)d_in[12];
    const float* nb_o_w = (const float*)d_in[13];
    const float* edge_w1 = (const float*)d_in[14];
    const float* edge_b1 = (const float*)d_in[15];
    const float* edge_w2 = (const float*)d_in[16];
    const float* edge_b2 = (const float*)d_in[17];
    const float* full_norm_w = (const float*)d_in[18];
    const float* full_q_w = (const float*)d_in[19];
    const float* full_k_w = (const float*)d_in[20];
    const float* full_v_w = (const float*)d_in[21];
    const float* full_o_w = (const float*)d_in[22];
    const float* feat_norm_w = (const float*)d_in[23];
    const float* feat_t_w = (const float*)d_in[24];
    const float* feat_t_b = (const float*)d_in[25];
    const float* feat_g_w = (const float*)d_in[26];
    const float* feat_g_b = (const float*)d_in[27];
    const float* ffn_norm_w = (const float*)d_in[28];
    const float* ffn_gate_w = (const float*)d_in[29];
    const float* ffn_up_w = (const float*)d_in[30];
    const float* ffn_down_w = (const float*)d_in[31];

    // ---- workspace carve (256B aligned) ----
    char* wsp = (char*)d_ws;
    size_t off = 0;
    auto alloc = [&](size_t bytes) -> void* {
        void* p = wsp + off;
        off += (bytes + 255) & ~(size_t)255;
        return p;
    };
    float* x    = (float*)alloc((size_t)N * D * 4);
    float* qkvb = (float*)alloc((size_t)N * 768 * 4);
    float* ao   = (float*)alloc((size_t)N * D * 4);      // t (fp32)
    float* tmp  = (float*)alloc((size_t)N * D * 4);      // gate pre-act
    float* sc   = (float*)alloc((size_t)H * NN * 4);     // fp32 scores
    float* eb   = (float*)alloc((size_t)NN * H * 4);     // edge bias
    float* guv  = (float*)alloc((size_t)N * 2048 * 4);   // ffn gate|up
    u16* scb  = (u16*)alloc((size_t)H * NN * 2);         // bf16 probs
    u16* aob  = (u16*)alloc((size_t)N * D * 2);
    u16* xnb  = (u16*)alloc((size_t)N * D * 2);
    u16* tb   = (u16*)alloc((size_t)N * D * 2);
    u16* hb   = (u16*)alloc((size_t)N * F * 2);
    u16* vbt  = (u16*)alloc((size_t)D * N * 2);
    u16* wqkvt[3];
    u16* wot[3];
    for (int a = 0; a < 3; a++) {
        wqkvt[a] = (u16*)alloc((size_t)768 * 256 * 2);
        wot[a]   = (u16*)alloc((size_t)256 * 256 * 2);
    }
    u16* wtt  = (u16*)alloc((size_t)256 * 256 * 2);
    u16* wg1t = (u16*)alloc((size_t)256 * 256 * 2);
    u16* wg2t = (u16*)alloc((size_t)256 * 256 * 2);
    u16* wgut = (u16*)alloc((size_t)2048 * 256 * 2);
    u16* wdt  = (u16*)alloc((size_t)256 * 1024 * 2);

    auto tr = [&](const float* in, long ldin, u16* out, int K, int Nc) {
        transpose_bf16_kernel<<<dim3(Nc / 32, K / 32), 256, 0, stream>>>(in, ldin, out, K, Nc);
    };

    // ---- weight transposes (once, independent) ----
    const float* qw[3] = {role_q_w, nb_q_w, full_q_w};
    const float* kw[3] = {role_k_w, nb_k_w, full_k_w};
    const float* vw[3] = {role_v_w, nb_v_w, full_v_w};
    const float* ow[3] = {role_o_w, nb_o_w, full_o_w};
    for (int a = 0; a < 3; a++) {
        tr(qw[a], D, wqkvt[a], D, D);
        tr(kw[a], D, wqkvt[a] + 256 * 256, D, D);
        tr(vw[a], D, wqkvt[a] + 512 * 256, D, D);
        tr(ow[a], D, wot[a], D, D);
    }
    tr(feat_t_w, D, wtt, D, D);
    tr(feat_g_w, D, wg1t, D, D);
    tr(feat_g_w + (size_t)D * D, D, wg2t, D, D);
    tr(ffn_gate_w, F, wgut, D, F);                 // -> [1024][256]
    tr(ffn_up_w, F, wgut + (size_t)F * 256, D, F); // -> rows 1024..2047
    tr(ffn_down_w, D, wdt, F, D);                  // -> [256][1024]

    // x = features; edge bias
    copy4_kernel<<<(N * D / 4) / 256, 256, 0, stream>>>((const float4*)features, (float4*)x, N * D / 4);
    edge_mlp_mfma_kernel<<<N, 256, 0, stream>>>(edge_feats, edge_w1, edge_b1, edge_w2, edge_b2, eb);

    dim3 sgrid(16, 16, 8);
    const float* nw[3] = {role_norm_w, nb_norm_w, full_norm_w};

    for (int a = 0; a < 3; a++) {
        rmsnorm_bf16_kernel<<<N, 256, 0, stream>>>(x, nw[a], xnb);
        // fused qkv projection: [1024,256] @ [256,768]
        bgemm_kernel<4, 0, false, false, false><<<dim3(768 / 64, N / 64, 1), 256, 0, stream>>>(
            xnb, wqkvt[a], nullptr, qkvb, N, 256, 768, 768, 0, 0, 0);
        if (a == 0)
            scores_kernel<1, false><<<sgrid, 256, 0, stream>>>(qkvb, qkvb + 256, 768, nullptr, role_idx, nullptr, sc);
        else if (a == 1)
            scores_kernel<2, true><<<sgrid, 256, 0, stream>>>(qkvb, qkvb + 256, 768, eb, nullptr, adjacency, sc);
        else
            scores_kernel<0, false><<<sgrid, 256, 0, stream>>>(qkvb, qkvb + 256, 768, nullptr, nullptr, nullptr, sc);
        softmax_kernel<<<H * N, 256, 0, stream>>>(sc, scb);
        // v^T: [1024 rows j][cols 512..767 of qkvb] -> vbt [256][1024]
        tr(qkvb + 512, 768, vbt, N, D);
        // PV: per head  [1024 x 1024] @ [1024 x 32] -> aob bf16
        bgemm_kernel<2, 0, false, false, true><<<dim3(1, N / 64, H), 256, 0, stream>>>(
            scb, vbt, nullptr, aob, N, N, HD, D, (long)NN, (long)HD * N, (long)HD);
        // o-projection, accumulate into x
        bgemm_kernel<4, 0, true, false, false><<<dim3(D / 64, N / 64, 1), 256, 0, stream>>>(
            aob, wot[a], nullptr, x, N, 256, D, D, 0, 0, 0);
    }

    // ---- 4. feature mixing ----
    rmsnorm_bf16_kernel<<<N, 256, 0, stream>>>(x, feat_norm_w, xnb);
    bgemm_kernel<4, 1, false, true, false><<<dim3(D / 64, N / 64, 1), 256, 0, stream>>>(
        xnb, wtt, feat_t_b, ao, N, 256, D, D, 0, 0, 0);                    // t = silu(.)
    cvt_bf16_kernel<<<(N * D) / 256, 256, 0, stream>>>(ao, tb, N * D);
    bgemm_kernel<4, 0, false, true, false><<<dim3(D / 64, N / 64, 1), 256, 0, stream>>>(
        xnb, wg1t, feat_g_b, tmp, N, 256, D, D, 0, 0, 0);                  // tmp = xn@G1+b
    bgemm_kernel<4, 0, true, false, false><<<dim3(D / 64, N / 64, 1), 256, 0, stream>>>(
        tb, wg2t, nullptr, tmp, N, 256, D, D, 0, 0, 0);                    // tmp += t@G2
    gate_combine_kernel<<<(N * D) / 256, 256, 0, stream>>>(tmp, ao, x, N * D);

    // ---- 5. gated FFN ----
    rmsnorm_bf16_kernel<<<N, 256, 0, stream>>>(x, ffn_norm_w, xnb);
    bgemm_kernel<4, 0, false, false, false><<<dim3(2048 / 64, N / 64, 1), 256, 0, stream>>>(
        xnb, wgut, nullptr, guv, N, 256, 2048, 2048, 0, 0, 0);             // gate|up
    ffn_mulcvt_kernel<<<(N * F) / 256, 256, 0, stream>>>(guv, hb);
    bgemm_kernel<4, 0, true, false, false><<<dim3(D / 64, N / 64, 1), 256, 0, stream>>>(
        hb, wdt, nullptr, x, N, 1024, D, D, 0, 0, 0);                      // x += h@down
    copy4_kernel<<<(N * D / 4) / 256, 256, 0, stream>>>((const float4*)x, (float4*)d_out, N * D / 4);
}

// Round 8
// 537.855 us; speedup vs baseline: 2.6776x; 1.2751x over previous
//
#include <hip/hip_runtime.h>
#include <math.h>

#define N 1024
#define D 256
#define E 16
#define H 8
#define HD 32
#define F 1024
#define NN (1024 * 1024)
#define SCALE 0.17677669529663687f /* 1/sqrt(32) */
#define EPS 1e-6f

typedef unsigned short u16;
typedef __attribute__((ext_vector_type(8))) short bfrag8;
typedef __attribute__((ext_vector_type(4))) float accf4;

// ---------------- helpers ----------------
__device__ __forceinline__ float block_sum(float v) {
    #pragma unroll
    for (int off = 32; off > 0; off >>= 1) v += __shfl_xor(v, off);
    __shared__ float ws[4];
    if ((threadIdx.x & 63) == 0) ws[threadIdx.x >> 6] = v;
    __syncthreads();
    v = ws[0] + ws[1] + ws[2] + ws[3];
    __syncthreads();
    return v;
}

__device__ __forceinline__ float silu_f(float x) { return x / (1.f + __expf(-x)); }
__device__ __forceinline__ float sigmoid_f(float x) { return 1.f / (1.f + __expf(-x)); }

__device__ __forceinline__ u16 f2bf(float x) {
    union { float f; unsigned int u; } c;
    c.f = x;
    unsigned int r = c.u + 0x7fffu + ((c.u >> 16) & 1u);
    return (u16)(r >> 16);
}

__device__ __forceinline__ unsigned int cvt_pk_bf16(float a, float b) {
    unsigned int r;
    asm("v_cvt_pk_bf16_f32 %0, %1, %2" : "=v"(r) : "v"(a), "v"(b));
    return r;
}

// ---------------- elementwise ----------------
__global__ void copy4_kernel(const float4* __restrict__ a, float4* __restrict__ b, int n4) {
    int i = blockIdx.x * 256 + threadIdx.x;
    if (i < n4) b[i] = a[i];
}

// x += sigmoid(g) * t
__global__ void gate_combine_kernel(const float* __restrict__ g, const float* __restrict__ t,
                                    float* __restrict__ x, int n) {
    int i = blockIdx.x * 256 + threadIdx.x;
    if (i < n) x[i] += sigmoid_f(g[i]) * t[i];
}

__global__ void cvt_bf16_kernel(const float* __restrict__ in, u16* __restrict__ out, int n) {
    int i = blockIdx.x * 256 + threadIdx.x;
    if (i < n) out[i] = f2bf(in[i]);
}

// hb[j,f] = bf16( silu(guv[j,f]) * guv[j,F+f] )
__global__ void ffn_mulcvt_kernel(const float* __restrict__ guv, u16* __restrict__ hb) {
    int i = blockIdx.x * 256 + threadIdx.x;
    int j = i >> 10, f = i & 1023;
    float g = guv[(long)j * 2048 + f];
    float u = guv[(long)j * 2048 + 1024 + f];
    hb[i] = f2bf(silu_f(g) * u);
}

// ---------------- rmsnorm -> bf16: one block per row, D=256 ----------------
__global__ void rmsnorm_bf16_kernel(const float* __restrict__ x, const float* __restrict__ w,
                                    u16* __restrict__ out) {
    int row = blockIdx.x;
    int t = threadIdx.x;
    float v = x[(long)row * D + t];
    float s = block_sum(v * v);
    float rms = sqrtf(s * (1.f / D) + EPS);
    out[(long)row * D + t] = f2bf(v / rms * w[t]);
}

// ---------------- transpose+convert: in fp32 [K][ldin] block -> out bf16 [Nc][K] ------
__global__ void transpose_bf16_kernel(const float* __restrict__ in, long ldin,
                                      u16* __restrict__ out, int K, int Nc) {
    __shared__ float tile[32][33];
    int k0 = blockIdx.y * 32, n0 = blockIdx.x * 32;
    int c = threadIdx.x & 31, r8 = threadIdx.x >> 5;
    #pragma unroll
    for (int i = 0; i < 4; i++) {
        int r = r8 + i * 8;
        tile[r][c] = in[(long)(k0 + r) * ldin + n0 + c];
    }
    __syncthreads();
    #pragma unroll
    for (int i = 0; i < 4; i++) {
        int r = r8 + i * 8;
        out[(long)(n0 + r) * K + k0 + c] = f2bf(tile[c][r]);
    }
}

// ---------------- bf16 MFMA GEMM ----------------
// C[M][ldc] (+)= act(A[M][K] @ B^T[Nc][K] + bias); A,B bf16 row-major (B pre-transposed).
// 4 waves; tile 64 x NTW*16; LDS rows padded to 72 u16.
// A-frag: row = lane&15, k = (lane>>4)*8+j.  C: row=(lane>>4)*4+reg, col=lane&15 (m89, HW-verified r6).
template <int NTW, int ACT, bool ACCUM, bool BIAS, bool BF16O>
__global__ __launch_bounds__(256) void bgemm_kernel(
    const u16* __restrict__ A, const u16* __restrict__ B, const float* __restrict__ bias,
    void* __restrict__ C, int M, int K, int Nc, int ldc, long sA, long sB, long sC) {
    constexpr int NTILE = NTW * 16;
    __shared__ __align__(16) u16 Asm[64 * 72];
    __shared__ __align__(16) u16 Bsm[NTILE * 72];
    A += (long)blockIdx.z * sA;
    B += (long)blockIdx.z * sB;
    long cbase = (long)blockIdx.z * sC;
    int m0 = blockIdx.y * 64, n0 = blockIdx.x * NTILE;
    int t = threadIdx.x;
    int wave = t >> 6, lane = t & 63, lg = lane >> 4, lr = lane & 15;
    accf4 acc[NTW] = {};
    for (int k0 = 0; k0 < K; k0 += 64) {
        #pragma unroll
        for (int c = 0; c < 2; c++) {
            int flat = c * 4096 + t * 16;
            int row = flat >> 7, col = (flat & 127) >> 1;
            *(int4*)&Asm[row * 72 + col] = *(const int4*)&A[(long)(m0 + row) * K + k0 + col];
        }
        #pragma unroll
        for (int c = 0; c < NTW / 2; c++) {
            int flat = c * 4096 + t * 16;
            int row = flat >> 7, col = (flat & 127) >> 1;
            *(int4*)&Bsm[row * 72 + col] = *(const int4*)&B[(long)(n0 + row) * K + k0 + col];
        }
        __syncthreads();
        #pragma unroll
        for (int ks = 0; ks < 2; ks++) {
            bfrag8 af = *(const bfrag8*)&Asm[(wave * 16 + lr) * 72 + ks * 32 + lg * 8];
            #pragma unroll
            for (int nt = 0; nt < NTW; nt++) {
                bfrag8 bf = *(const bfrag8*)&Bsm[(nt * 16 + lr) * 72 + ks * 32 + lg * 8];
                acc[nt] = __builtin_amdgcn_mfma_f32_16x16x32_bf16(af, bf, acc[nt], 0, 0, 0);
            }
        }
        __syncthreads();
    }
    float* Cf = (float*)C;
    u16* Cb = (u16*)C;
    #pragma unroll
    for (int nt = 0; nt < NTW; nt++) {
        int gn = n0 + nt * 16 + lr;
        #pragma unroll
        for (int r = 0; r < 4; r++) {
            int gm = m0 + wave * 16 + lg * 4 + r;
            float v = acc[nt][r];
            if (BIAS) v += bias[gn];
            if (ACT == 1) v = silu_f(v);
            long idx = cbase + (long)gm * ldc + gn;
            if (BF16O) Cb[idx] = f2bf(v);
            else if (ACCUM) Cf[idx] += v;
            else Cf[idx] = v;
        }
    }
}

// ---------------- fused flash attention ----------------
// Block = 4 waves: wave w -> i-subtile (w>>1)*16, j-half (w&1)*512. Grid (32 i-blocks, 8 heads).
// Per 64-j tile: S^T = mfma(K-rows, Q-cols) -> lane owns col i=lane&15, rows j=(lane>>4)*4+r.
// Online softmax per i (2 shfl_xor over lg-groups). P packed bf16 into per-wave LDS rows [i][j]
// (stride 72). PV: O^T[d][i] += mfma(V^T-rows, P^T) with B-frag = contiguous row read of P_lds.
// j-halves merged via (m,l)-rescale through LDS. MASK: 0 none, 1 role, 2 neighbor(+ebT bias).
template <int MASK>
__global__ __launch_bounds__(256) void flash_attn_kernel(
    const u16* __restrict__ qkvbf, const u16* __restrict__ vbt,
    const float* __restrict__ ebT, const int* __restrict__ roles,
    const int* __restrict__ adj, u16* __restrict__ aob) {
    __shared__ int roles_s[N];
    __shared__ __align__(16) u16 P_lds[4][16][72];
    __shared__ float mrg_m[4][16], mrg_l[4][16];
    __shared__ __align__(16) float mrg_O[2][32][16];

    int h = blockIdx.y;
    int t = threadIdx.x, wave = t >> 6, lane = t & 63;
    int lg = lane >> 4, lr = lane & 15;
    int iw = wave >> 1, jh = wave & 1;
    int i = blockIdx.x * 32 + iw * 16 + lr;   // lane's output column i

    if (MASK == 1) {
        #pragma unroll
        for (int c = 0; c < 4; c++) roles_s[t + c * 256] = roles[t + c * 256];
    }
    __syncthreads();

    bfrag8 qf = *(const bfrag8*)&qkvbf[(long)i * 768 + h * HD + lg * 8];
    int role_i = (MASK == 1) ? roles_s[i] : 0;

    accf4 o0 = {0.f, 0.f, 0.f, 0.f}, o1 = {0.f, 0.f, 0.f, 0.f};
    float m_run = -1e30f, l_run = 0.f;

    for (int jt = 0; jt < 8; jt++) {
        int j0 = jh * 512 + jt * 64;
        float p[16];
        float tmax = -1e30f;
        #pragma unroll
        for (int js = 0; js < 4; js++) {
            bfrag8 kf = *(const bfrag8*)&qkvbf[(long)(j0 + js * 16 + lr) * 768 + 256 + h * HD + lg * 8];
            accf4 z = {0.f, 0.f, 0.f, 0.f};
            accf4 s = __builtin_amdgcn_mfma_f32_16x16x32_bf16(kf, qf, z, 0, 0, 0);
            float4 eb4;
            int4 ad4;
            if (MASK == 2) {
                eb4 = *(const float4*)&ebT[(long)h * NN + (long)i * N + j0 + js * 16 + lg * 4];
                ad4 = *(const int4*)&adj[(long)i * N + j0 + js * 16 + lg * 4];
            }
            #pragma unroll
            for (int r = 0; r < 4; r++) {
                int j = j0 + js * 16 + lg * 4 + r;
                float val = s[r] * SCALE;
                bool keep = true;
                if (MASK == 2) {
                    val += (r == 0) ? eb4.x : (r == 1) ? eb4.y : (r == 2) ? eb4.z : eb4.w;
                    int av = (r == 0) ? ad4.x : (r == 1) ? ad4.y : (r == 2) ? ad4.z : ad4.w;
                    keep = (av > 0) || (i == j);
                }
                if (MASK == 1) keep = (roles_s[j] == role_i);
                val = keep ? val : -1e30f;
                p[js * 4 + r] = val;
                tmax = fmaxf(tmax, val);
            }
        }
        tmax = fmaxf(tmax, __shfl_xor(tmax, 16));
        tmax = fmaxf(tmax, __shfl_xor(tmax, 32));
        float m_new = fmaxf(m_run, tmax);
        float alpha = __expf(m_run - m_new);  // both -1e30 -> 1 (harmless: wiped by merge/later tiles)
        float lsum = 0.f;
        #pragma unroll
        for (int v = 0; v < 16; v++) {
            float pe = __expf(p[v] - m_new);
            p[v] = pe;
            lsum += pe;
        }
        lsum += __shfl_xor(lsum, 16);
        lsum += __shfl_xor(lsum, 32);
        l_run = l_run * alpha + lsum;
        m_run = m_new;
        #pragma unroll
        for (int r = 0; r < 4; r++) { o0[r] *= alpha; o1[r] *= alpha; }
        // pack P -> per-wave LDS rows [i_local = lr][j_local]
        #pragma unroll
        for (int js = 0; js < 4; js++) {
            uint2 pk;
            pk.x = cvt_pk_bf16(p[js * 4 + 0], p[js * 4 + 1]);
            pk.y = cvt_pk_bf16(p[js * 4 + 2], p[js * 4 + 3]);
            *(uint2*)&P_lds[wave][lr][js * 16 + lg * 4] = pk;
        }
        // PV: O^T[d][i] += V^T @ P^T (same-wave LDS RAW, compiler-ordered)
        #pragma unroll
        for (int ks = 0; ks < 2; ks++) {
            bfrag8 pb = *(const bfrag8*)&P_lds[wave][lr][ks * 32 + lg * 8];
            bfrag8 v0 = *(const bfrag8*)&vbt[(long)(h * HD + lr) * N + j0 + ks * 32 + lg * 8];
            bfrag8 v1 = *(const bfrag8*)&vbt[(long)(h * HD + 16 + lr) * N + j0 + ks * 32 + lg * 8];
            o0 = __builtin_amdgcn_mfma_f32_16x16x32_bf16(v0, pb, o0, 0, 0, 0);
            o1 = __builtin_amdgcn_mfma_f32_16x16x32_bf16(v1, pb, o1, 0, 0, 0);
        }
    }

    // ---- merge the two j-halves (wave pairs share i-range) ----
    if (lg == 0) { mrg_m[wave][lr] = m_run; mrg_l[wave][lr] = l_run; }
    __syncthreads();
    int other = wave ^ 1;
    float m_o = mrg_m[other][lr], l_o = mrg_l[other][lr];
    float m_tot = fmaxf(m_run, m_o);
    float a_s = __expf(m_run - m_tot);
    float a_o = __expf(m_o - m_tot);
    float inv = 1.f / (a_s * l_run + a_o * l_o);
    if (jh == 0) {
        #pragma unroll
        for (int r = 0; r < 4; r++) {
            mrg_O[iw][lg * 4 + r][lr] = a_s * o0[r];
            mrg_O[iw][16 + lg * 4 + r][lr] = a_s * o1[r];
        }
    }
    __syncthreads();
    if (jh == 1) {
        #pragma unroll
        for (int r = 0; r < 4; r++) {
            float f0 = (mrg_O[iw][lg * 4 + r][lr] + a_s * o0[r]) * inv;
            float f1 = (mrg_O[iw][16 + lg * 4 + r][lr] + a_s * o1[r]) * inv;
            aob[(long)i * D + h * HD + lg * 4 + r] = f2bf(f0);
            aob[(long)i * D + h * HD + 16 + lg * 4 + r] = f2bf(f1);
        }
    }
}

// ---------------- edge MLP via MFMA bf16 (output transposed: ebT[h][i][j]) --------
__global__ __launch_bounds__(256, 3) void edge_mlp_mfma_kernel(
    const float* __restrict__ ef, const float* __restrict__ w1, const float* __restrict__ b1,
    const float* __restrict__ w2, const float* __restrict__ b2, float* __restrict__ ebT) {
    __shared__ __align__(16) u16 w1t[256 * 16];
    __shared__ __align__(16) u16 w2t[16 * 256];
    __shared__ __align__(16) u16 hid[4][16 * 264];
    int t = threadIdx.x;
    int i = blockIdx.x;

    {
        int d = t;
        #pragma unroll
        for (int e = 0; e < 16; e++) w1t[d * 16 + e] = f2bf(w1[e * 256 + d]);
        float4 wa = *(const float4*)&w2[d * 8];
        float4 wb = *(const float4*)&w2[d * 8 + 4];
        w2t[0 * 256 + d] = f2bf(wa.x);
        w2t[1 * 256 + d] = f2bf(wa.y);
        w2t[2 * 256 + d] = f2bf(wa.z);
        w2t[3 * 256 + d] = f2bf(wa.w);
        w2t[4 * 256 + d] = f2bf(wb.x);
        w2t[5 * 256 + d] = f2bf(wb.y);
        w2t[6 * 256 + d] = f2bf(wb.z);
        w2t[7 * 256 + d] = f2bf(wb.w);
        #pragma unroll
        for (int h = 8; h < 16; h++) w2t[h * 256 + d] = 0;
    }
    __syncthreads();

    int wave = t >> 6, lane = t & 63;
    int lg = lane >> 4, lr = lane & 15;
    u16* hw = hid[wave];

    bfrag8 a1[16];
    #pragma unroll
    for (int dt = 0; dt < 16; dt++) {
        int d = dt * 16 + lr;
        if (lg < 2) {
            a1[dt] = *(const bfrag8*)&w1t[d * 16 + lg * 8];
        } else if (lg == 2) {
            union { unsigned int u[4]; bfrag8 s; } z = {{0u, 0u, 0u, 0u}};
            z.u[0] = (unsigned int)f2bf(b1[d]);
            a1[dt] = z.s;
        } else {
            union { unsigned int u[4]; bfrag8 s; } z = {{0u, 0u, 0u, 0u}};
            a1[dt] = z.s;
        }
    }
    bfrag8 a2[8];
    #pragma unroll
    for (int ks = 0; ks < 8; ks++)
        a2[ks] = *(const bfrag8*)&w2t[lr * 256 + ks * 32 + lg * 8];

    float b2v[4];
    #pragma unroll
    for (int r = 0; r < 4; r++) b2v[r] = (lg < 2) ? b2[lg * 4 + r] : 0.f;

    for (int it = 0; it < 16; it++) {
        long rowbase = (long)i * N + (it * 4 + wave) * 16;
        bfrag8 bfrag;
        if (lg < 2) {
            const float* p = &ef[(rowbase + lr) * E + lg * 8];
            float4 f0 = *(const float4*)p;
            float4 f1 = *(const float4*)(p + 4);
            union { unsigned int u[4]; bfrag8 s; } uu;
            uu.u[0] = cvt_pk_bf16(f0.x, f0.y);
            uu.u[1] = cvt_pk_bf16(f0.z, f0.w);
            uu.u[2] = cvt_pk_bf16(f1.x, f1.y);
            uu.u[3] = cvt_pk_bf16(f1.z, f1.w);
            bfrag = uu.s;
        } else {
            union { unsigned int u[4]; bfrag8 s; } uu = {{(lg == 2) ? 0x3f80u : 0u, 0u, 0u, 0u}};
            bfrag = uu.s;
        }
        #pragma unroll
        for (int dt = 0; dt < 16; dt++) {
            accf4 acc = {0.f, 0.f, 0.f, 0.f};
            acc = __builtin_amdgcn_mfma_f32_16x16x32_bf16(a1[dt], bfrag, acc, 0, 0, 0);
            float s0 = silu_f(acc[0]);
            float s1 = silu_f(acc[1]);
            float s2 = silu_f(acc[2]);
            float s3 = silu_f(acc[3]);
            uint2 pk;
            pk.x = cvt_pk_bf16(s0, s1);
            pk.y = cvt_pk_bf16(s2, s3);
            *(uint2*)&hw[lr * 264 + dt * 16 + lg * 4] = pk;
        }
        accf4 acc2 = {0.f, 0.f, 0.f, 0.f};
        #pragma unroll
        for (int ks = 0; ks < 8; ks++) {
            bfrag8 hb = *(const bfrag8*)&hw[lr * 264 + ks * 32 + lg * 8];
            acc2 = __builtin_amdgcn_mfma_f32_16x16x32_bf16(a2[ks], hb, acc2, 0, 0, 0);
        }
        if (lg < 2) {
            #pragma unroll
            for (int r = 0; r < 4; r++)
                ebT[(long)(lg * 4 + r) * NN + rowbase + lr] = acc2[r] + b2v[r];
        }
    }
}

// =====================================================================================
extern "C" void kernel_launch(void* const* d_in, const int* in_sizes, int n_in,
                              void* d_out, int out_size, void* d_ws, size_t ws_size,
                              hipStream_t stream) {
    const float* features   = (const float*)d_in[0];
    const int*   adjacency  = (const int*)d_in[1];
    const float* edge_feats = (const float*)d_in[2];
    const int*   role_idx   = (const int*)d_in[3];
    const float* role_norm_w = (const float*)d_in[4];
    const float* role_q_w = (const float*)d_in[5];
    const float* role_k_w = (const float*)d_in[6];
    const float* role_v_w = (const float*)d_in[7];
    const float* role_o_w = (const float*)d_in[8];
    const float* nb_norm_w = (const float*)d_in[9];
    const float* nb_q_w = (const float*)d_in[10];
    const float* nb_k_w = (const float*)d_in[11];
    const float* nb_v_w = (const float*)d_in[12];
    const float* nb_o_w = (const float*)d_in[13];
    const float* edge_w1 = (const float*)d_in[14];
    const float* edge_b1 = (const float*)d_in[15];
    const float* edge_w2 = (const float*)d_in[16];
    const float* edge_b2 = (const float*)d_in[17];
    const float* full_norm_w = (const float*)d_in[18];
    const float* full_q_w = (const float*)d_in[19];
    const float* full_k_w = (const float*)d_in[20];
    const float* full_v_w = (const float*)d_in[21];
    const float* full_o_w = (const float*)d_in[22];
    const float* feat_norm_w = (const float*)d_in[23];
    const float* feat_t_w = (const float*)d_in[24];
    const float* feat_t_b = (const float*)d_in[25];
    const float* feat_g_w = (const float*)d_in[26];
    const float* feat_g_b = (const float*)d_in[27];
    const float* ffn_norm_w = (const float*)d_in[28];
    const float* ffn_gate_w = (const float*)d_in[29];
    const float* ffn_up_w = (const float*)d_in[30];
    const float* ffn_down_w = (const float*)d_in[31];

    // ---- workspace carve (256B aligned) ----
    char* wsp = (char*)d_ws;
    size_t off = 0;
    auto alloc = [&](size_t bytes) -> void* {
        void* p = wsp + off;
        off += (bytes + 255) & ~(size_t)255;
        return p;
    };
    float* x    = (float*)alloc((size_t)N * D * 4);
    float* qkvb = (float*)alloc((size_t)N * 768 * 4);
    float* ao   = (float*)alloc((size_t)N * D * 4);      // t (fp32)
    float* tmp  = (float*)alloc((size_t)N * D * 4);      // gate pre-act
    float* eb   = (float*)alloc((size_t)H * NN * 4);     // ebT[h][i][j]
    float* guv  = (float*)alloc((size_t)N * 2048 * 4);   // ffn gate|up
    u16* qkvbf = (u16*)alloc((size_t)N * 768 * 2);
    u16* aob  = (u16*)alloc((size_t)N * D * 2);
    u16* xnb  = (u16*)alloc((size_t)N * D * 2);
    u16* tb   = (u16*)alloc((size_t)N * D * 2);
    u16* hb   = (u16*)alloc((size_t)N * F * 2);
    u16* vbt  = (u16*)alloc((size_t)D * N * 2);
    u16* wqkvt[3];
    u16* wot[3];
    for (int a = 0; a < 3; a++) {
        wqkvt[a] = (u16*)alloc((size_t)768 * 256 * 2);
        wot[a]   = (u16*)alloc((size_t)256 * 256 * 2);
    }
    u16* wtt  = (u16*)alloc((size_t)256 * 256 * 2);
    u16* wg1t = (u16*)alloc((size_t)256 * 256 * 2);
    u16* wg2t = (u16*)alloc((size_t)256 * 256 * 2);
    u16* wgut = (u16*)alloc((size_t)2048 * 256 * 2);
    u16* wdt  = (u16*)alloc((size_t)256 * 1024 * 2);

    auto tr = [&](const float* in, long ldin, u16* out, int K, int Nc) {
        transpose_bf16_kernel<<<dim3(Nc / 32, K / 32), 256, 0, stream>>>(in, ldin, out, K, Nc);
    };

    // ---- weight transposes (once, independent) ----
    const float* qw[3] = {role_q_w, nb_q_w, full_q_w};
    const float* kw[3] = {role_k_w, nb_k_w, full_k_w};
    const float* vw[3] = {role_v_w, nb_v_w, full_v_w};
    const float* ow[3] = {role_o_w, nb_o_w, full_o_w};
    for (int a = 0; a < 3; a++) {
        tr(qw[a], D, wqkvt[a], D, D);
        tr(kw[a], D, wqkvt[a] + 256 * 256, D, D);
        tr(vw[a], D, wqkvt[a] + 512 * 256, D, D);
        tr(ow[a], D, wot[a], D, D);
    }
    tr(feat_t_w, D, wtt, D, D);
    tr(feat_g_w, D, wg1t, D, D);
    tr(feat_g_w + (size_t)D * D, D, wg2t, D, D);
    tr(ffn_gate_w, F, wgut, D, F);
    tr(ffn_up_w, F, wgut + (size_t)F * 256, D, F);
    tr(ffn_down_w, D, wdt, F, D);

    // x = features; edge bias (transposed layout)
    copy4_kernel<<<(N * D / 4) / 256, 256, 0, stream>>>((const float4*)features, (float4*)x, N * D / 4);
    edge_mlp_mfma_kernel<<<N, 256, 0, stream>>>(edge_feats, edge_w1, edge_b1, edge_w2, edge_b2, eb);

    const float* nw[3] = {role_norm_w, nb_norm_w, full_norm_w};
    dim3 fgrid(N / 32, H);

    for (int a = 0; a < 3; a++) {
        rmsnorm_bf16_kernel<<<N, 256, 0, stream>>>(x, nw[a], xnb);
        // fused qkv projection: [1024,256] @ [256,768]
        bgemm_kernel<4, 0, false, false, false><<<dim3(768 / 64, N / 64, 1), 256, 0, stream>>>(
            xnb, wqkvt[a], nullptr, qkvb, N, 256, 768, 768, 0, 0, 0);
        cvt_bf16_kernel<<<(N * 768) / 256, 256, 0, stream>>>(qkvb, qkvbf, N * 768);
        tr(qkvb + 512, 768, vbt, N, D);   // V^T bf16 [256][1024]
        if (a == 0)
            flash_attn_kernel<1><<<fgrid, 256, 0, stream>>>(qkvbf, vbt, nullptr, role_idx, nullptr, aob);
        else if (a == 1)
            flash_attn_kernel<2><<<fgrid, 256, 0, stream>>>(qkvbf, vbt, eb, nullptr, adjacency, aob);
        else
            flash_attn_kernel<0><<<fgrid, 256, 0, stream>>>(qkvbf, vbt, nullptr, nullptr, nullptr, aob);
        // o-projection, accumulate into x
        bgemm_kernel<4, 0, true, false, false><<<dim3(D / 64, N / 64, 1), 256, 0, stream>>>(
            aob, wot[a], nullptr, x, N, 256, D, D, 0, 0, 0);
    }

    // ---- 4. feature mixing ----
    rmsnorm_bf16_kernel<<<N, 256, 0, stream>>>(x, feat_norm_w, xnb);
    bgemm_kernel<4, 1, false, true, false><<<dim3(D / 64, N / 64, 1), 256, 0, stream>>>(
        xnb, wtt, feat_t_b, ao, N, 256, D, D, 0, 0, 0);                    // t = silu(.)
    cvt_bf16_kernel<<<(N * D) / 256, 256, 0, stream>>>(ao, tb, N * D);
    bgemm_kernel<4, 0, false, true, false><<<dim3(D / 64, N / 64, 1), 256, 0, stream>>>(
        xnb, wg1t, feat_g_b, tmp, N, 256, D, D, 0, 0, 0);                  // tmp = xn@G1+b
    bgemm_kernel<4, 0, true, false, false><<<dim3(D / 64, N / 64, 1), 256, 0, stream>>>(
        tb, wg2t, nullptr, tmp, N, 256, D, D, 0, 0, 0);                    // tmp += t@G2
    gate_combine_kernel<<<(N * D) / 256, 256, 0, stream>>>(tmp, ao, x, N * D);

    // ---- 5. gated FFN ----
    rmsnorm_bf16_kernel<<<N, 256, 0, stream>>>(x, ffn_norm_w, xnb);
    bgemm_kernel<4, 0, false, false, false><<<dim3(2048 / 64, N / 64, 1), 256, 0, stream>>>(
        xnb, wgut, nullptr, guv, N, 256, 2048, 2048, 0, 0, 0);             // gate|up
    ffn_mulcvt_kernel<<<(N * F) / 256, 256, 0, stream>>>(guv, hb);
    bgemm_kernel<4, 0, true, false, false><<<dim3(D / 64, N / 64, 1), 256, 0, stream>>>(
        hb, wdt, nullptr, x, N, 1024, D, D, 0, 0, 0);                      // x += h@down
    copy4_kernel<<<(N * D / 4) / 256, 256, 0, stream>>>((const float4*)x, (float4*)d_out, N * D / 4);
}

// Round 11
// 491.414 us; speedup vs baseline: 2.9307x; 1.0945x over previous
//
#include <hip/hip_runtime.h>
#include <math.h>

#define N 1024
#define D 256
#define E 16
#define H 8
#define HD 32
#define F 1024
#define NN (1024 * 1024)
#define SCALE 0.17677669529663687f /* 1/sqrt(32) */
#define EPS 1e-6f

typedef unsigned short u16;
typedef __attribute__((ext_vector_type(8))) short bfrag8;
typedef __attribute__((ext_vector_type(4))) float accf4;

// ---------------- helpers ----------------
__device__ __forceinline__ float block_sum(float v) {
    #pragma unroll
    for (int off = 32; off > 0; off >>= 1) v += __shfl_xor(v, off);
    __shared__ float ws[4];
    if ((threadIdx.x & 63) == 0) ws[threadIdx.x >> 6] = v;
    __syncthreads();
    v = ws[0] + ws[1] + ws[2] + ws[3];
    __syncthreads();
    return v;
}

__device__ __forceinline__ float silu_f(float x) { return x / (1.f + __expf(-x)); }
__device__ __forceinline__ float sigmoid_f(float x) { return 1.f / (1.f + __expf(-x)); }

__device__ __forceinline__ u16 f2bf(float x) {
    union { float f; unsigned int u; } c;
    c.f = x;
    unsigned int r = c.u + 0x7fffu + ((c.u >> 16) & 1u);
    return (u16)(r >> 16);
}

__device__ __forceinline__ float bf2f(u16 v) {
    union { unsigned int u; float f; } c;
    c.u = ((unsigned int)v) << 16;
    return c.f;
}

__device__ __forceinline__ unsigned int cvt_pk_bf16(float a, float b) {
    unsigned int r;
    asm("v_cvt_pk_bf16_f32 %0, %1, %2" : "=v"(r) : "v"(a), "v"(b));
    return r;
}

// ---------------- elementwise ----------------
__global__ void copy4_kernel(const float4* __restrict__ a, float4* __restrict__ b, int n4) {
    int i = blockIdx.x * 256 + threadIdx.x;
    if (i < n4) b[i] = a[i];
}

// x += sigmoid(g) * t   (t in bf16)
__global__ void gate_combine_kernel(const float* __restrict__ g, const u16* __restrict__ t,
                                    float* __restrict__ x, int n) {
    int i = blockIdx.x * 256 + threadIdx.x;
    if (i < n) x[i] += sigmoid_f(g[i]) * bf2f(t[i]);
}

// hb[j,f] = bf16( silu(guv[j,f]) * guv[j,F+f] ), guv in bf16
__global__ void ffn_mulcvt_kernel(const u16* __restrict__ guv, u16* __restrict__ hb) {
    int i = blockIdx.x * 256 + threadIdx.x;
    int j = i >> 10, f = i & 1023;
    float g = bf2f(guv[(long)j * 2048 + f]);
    float u = bf2f(guv[(long)j * 2048 + 1024 + f]);
    hb[i] = f2bf(silu_f(g) * u);
}

// ---------------- rmsnorm -> bf16: one block per row, D=256 ----------------
__global__ void rmsnorm_bf16_kernel(const float* __restrict__ x, const float* __restrict__ w,
                                    u16* __restrict__ out) {
    int row = blockIdx.x;
    int t = threadIdx.x;
    float v = x[(long)row * D + t];
    float s = block_sum(v * v);
    float rms = sqrtf(s * (1.f / D) + EPS);
    out[(long)row * D + t] = f2bf(v / rms * w[t]);
}

// ---------------- transposes ----------------
// generic: in fp32 [K][ldin] -> out bf16 [Nc][K]
__global__ void transpose_bf16_kernel(const float* __restrict__ in, long ldin,
                                      u16* __restrict__ out, int K, int Nc) {
    __shared__ float tile[32][33];
    int k0 = blockIdx.y * 32, n0 = blockIdx.x * 32;
    int c = threadIdx.x & 31, r8 = threadIdx.x >> 5;
    #pragma unroll
    for (int i = 0; i < 4; i++) {
        int r = r8 + i * 8;
        tile[r][c] = in[(long)(k0 + r) * ldin + n0 + c];
    }
    __syncthreads();
    #pragma unroll
    for (int i = 0; i < 4; i++) {
        int r = r8 + i * 8;
        out[(long)(n0 + r) * K + k0 + c] = f2bf(tile[c][r]);
    }
}

// batched 256x256 fp32->bf16 transposes (15 weights in one launch), dst contiguous
struct Src15 { const float* p[15]; };
__global__ void transpose15_kernel(Src15 srcs, u16* __restrict__ wall) {
    __shared__ float tile[32][33];
    const float* in = srcs.p[blockIdx.z];
    u16* out = wall + (size_t)blockIdx.z * 65536;
    int k0 = blockIdx.y * 32, n0 = blockIdx.x * 32;
    int c = threadIdx.x & 31, r8 = threadIdx.x >> 5;
    #pragma unroll
    for (int i = 0; i < 4; i++) {
        int r = r8 + i * 8;
        tile[r][c] = in[(long)(k0 + r) * 256 + n0 + c];
    }
    __syncthreads();
    #pragma unroll
    for (int i = 0; i < 4; i++) {
        int r = r8 + i * 8;
        out[(long)(n0 + r) * 256 + k0 + c] = f2bf(tile[c][r]);
    }
}

// batched gate/up [256][1024] -> bf16 [1024][256], z=2
struct Src2 { const float* p[2]; };
__global__ void transpose_gu_kernel(Src2 srcs, u16* __restrict__ wgut) {
    __shared__ float tile[32][33];
    const float* in = srcs.p[blockIdx.z];
    u16* out = wgut + (size_t)blockIdx.z * (size_t)F * 256;
    int k0 = blockIdx.y * 32, n0 = blockIdx.x * 32;
    int c = threadIdx.x & 31, r8 = threadIdx.x >> 5;
    #pragma unroll
    for (int i = 0; i < 4; i++) {
        int r = r8 + i * 8;
        tile[r][c] = in[(long)(k0 + r) * F + n0 + c];
    }
    __syncthreads();
    #pragma unroll
    for (int i = 0; i < 4; i++) {
        int r = r8 + i * 8;
        out[(long)(n0 + r) * 256 + k0 + c] = f2bf(tile[c][r]);
    }
}

// u16 -> u16 transpose: in [K][ldin] -> out [Nc][K]
__global__ void transpose_u16_kernel(const u16* __restrict__ in, long ldin,
                                     u16* __restrict__ out, int K, int Nc) {
    __shared__ u16 tile[32][34];
    int k0 = blockIdx.y * 32, n0 = blockIdx.x * 32;
    int c = threadIdx.x & 31, r8 = threadIdx.x >> 5;
    #pragma unroll
    for (int i = 0; i < 4; i++) {
        int r = r8 + i * 8;
        tile[r][c] = in[(long)(k0 + r) * ldin + n0 + c];
    }
    __syncthreads();
    #pragma unroll
    for (int i = 0; i < 4; i++) {
        int r = r8 + i * 8;
        out[(long)(n0 + r) * K + k0 + c] = tile[c][r];
    }
}

// ---------------- bf16 MFMA GEMM ----------------
// C[M][ldc] (+)= act(A[M][K] @ B^T[Nc][K] + bias); A,B bf16 row-major (B pre-transposed).
// 4 waves; tile 64 x NTW*16; LDS rows padded to 72 u16.
// A-frag: row = lane&15, k = (lane>>4)*8+j.  C: row=(lane>>4)*4+reg, col=lane&15 (HW-verified r6).
template <int NTW, int ACT, bool ACCUM, bool BIAS, bool BF16O>
__global__ __launch_bounds__(256) void bgemm_kernel(
    const u16* __restrict__ A, const u16* __restrict__ B, const float* __restrict__ bias,
    void* __restrict__ C, int M, int K, int Nc, int ldc, long sA, long sB, long sC) {
    constexpr int NTILE = NTW * 16;
    __shared__ __align__(16) u16 Asm[64 * 72];
    __shared__ __align__(16) u16 Bsm[NTILE * 72];
    A += (long)blockIdx.z * sA;
    B += (long)blockIdx.z * sB;
    long cbase = (long)blockIdx.z * sC;
    int m0 = blockIdx.y * 64, n0 = blockIdx.x * NTILE;
    int t = threadIdx.x;
    int wave = t >> 6, lane = t & 63, lg = lane >> 4, lr = lane & 15;
    accf4 acc[NTW] = {};
    for (int k0 = 0; k0 < K; k0 += 64) {
        #pragma unroll
        for (int c = 0; c < 2; c++) {
            int flat = c * 4096 + t * 16;
            int row = flat >> 7, col = (flat & 127) >> 1;
            *(int4*)&Asm[row * 72 + col] = *(const int4*)&A[(long)(m0 + row) * K + k0 + col];
        }
        #pragma unroll
        for (int c = 0; c < NTW / 2; c++) {
            int flat = c * 4096 + t * 16;
            int row = flat >> 7, col = (flat & 127) >> 1;
            *(int4*)&Bsm[row * 72 + col] = *(const int4*)&B[(long)(n0 + row) * K + k0 + col];
        }
        __syncthreads();
        #pragma unroll
        for (int ks = 0; ks < 2; ks++) {
            bfrag8 af = *(const bfrag8*)&Asm[(wave * 16 + lr) * 72 + ks * 32 + lg * 8];
            #pragma unroll
            for (int nt = 0; nt < NTW; nt++) {
                bfrag8 bf = *(const bfrag8*)&Bsm[(nt * 16 + lr) * 72 + ks * 32 + lg * 8];
                acc[nt] = __builtin_amdgcn_mfma_f32_16x16x32_bf16(af, bf, acc[nt], 0, 0, 0);
            }
        }
        __syncthreads();
    }
    float* Cf = (float*)C;
    u16* Cb = (u16*)C;
    #pragma unroll
    for (int nt = 0; nt < NTW; nt++) {
        int gn = n0 + nt * 16 + lr;
        #pragma unroll
        for (int r = 0; r < 4; r++) {
            int gm = m0 + wave * 16 + lg * 4 + r;
            float v = acc[nt][r];
            if (BIAS) v += bias[gn];
            if (ACT == 1) v = silu_f(v);
            long idx = cbase + (long)gm * ldc + gn;
            if (BF16O) Cb[idx] = f2bf(v);
            else if (ACCUM) Cf[idx] += v;
            else Cf[idx] = v;
        }
    }
}

// ---------------- fused flash attention (unchanged from r6, HW-validated r8) ----------
template <int MASK>
__global__ __launch_bounds__(256) void flash_attn_kernel(
    const u16* __restrict__ qkvbf, const u16* __restrict__ vbt,
    const float* __restrict__ ebT, const int* __restrict__ roles,
    const int* __restrict__ adj, u16* __restrict__ aob) {
    __shared__ int roles_s[N];
    __shared__ __align__(16) u16 P_lds[4][16][72];
    __shared__ float mrg_m[4][16], mrg_l[4][16];
    __shared__ __align__(16) float mrg_O[2][32][16];

    int h = blockIdx.y;
    int t = threadIdx.x, wave = t >> 6, lane = t & 63;
    int lg = lane >> 4, lr = lane & 15;
    int iw = wave >> 1, jh = wave & 1;
    int i = blockIdx.x * 32 + iw * 16 + lr;

    if (MASK == 1) {
        #pragma unroll
        for (int c = 0; c < 4; c++) roles_s[t + c * 256] = roles[t + c * 256];
    }
    __syncthreads();

    bfrag8 qf = *(const bfrag8*)&qkvbf[(long)i * 768 + h * HD + lg * 8];
    int role_i = (MASK == 1) ? roles_s[i] : 0;

    accf4 o0 = {0.f, 0.f, 0.f, 0.f}, o1 = {0.f, 0.f, 0.f, 0.f};
    float m_run = -1e30f, l_run = 0.f;

    for (int jt = 0; jt < 8; jt++) {
        int j0 = jh * 512 + jt * 64;
        float p[16];
        float tmax = -1e30f;
        #pragma unroll
        for (int js = 0; js < 4; js++) {
            bfrag8 kf = *(const bfrag8*)&qkvbf[(long)(j0 + js * 16 + lr) * 768 + 256 + h * HD + lg * 8];
            accf4 z = {0.f, 0.f, 0.f, 0.f};
            accf4 s = __builtin_amdgcn_mfma_f32_16x16x32_bf16(kf, qf, z, 0, 0, 0);
            float4 eb4;
            int4 ad4;
            if (MASK == 2) {
                eb4 = *(const float4*)&ebT[(long)h * NN + (long)i * N + j0 + js * 16 + lg * 4];
                ad4 = *(const int4*)&adj[(long)i * N + j0 + js * 16 + lg * 4];
            }
            #pragma unroll
            for (int r = 0; r < 4; r++) {
                int j = j0 + js * 16 + lg * 4 + r;
                float val = s[r] * SCALE;
                bool keep = true;
                if (MASK == 2) {
                    val += (r == 0) ? eb4.x : (r == 1) ? eb4.y : (r == 2) ? eb4.z : eb4.w;
                    int av = (r == 0) ? ad4.x : (r == 1) ? ad4.y : (r == 2) ? ad4.z : ad4.w;
                    keep = (av > 0) || (i == j);
                }
                if (MASK == 1) keep = (roles_s[j] == role_i);
                val = keep ? val : -1e30f;
                p[js * 4 + r] = val;
                tmax = fmaxf(tmax, val);
            }
        }
        tmax = fmaxf(tmax, __shfl_xor(tmax, 16));
        tmax = fmaxf(tmax, __shfl_xor(tmax, 32));
        float m_new = fmaxf(m_run, tmax);
        float alpha = __expf(m_run - m_new);
        float lsum = 0.f;
        #pragma unroll
        for (int v = 0; v < 16; v++) {
            float pe = __expf(p[v] - m_new);
            p[v] = pe;
            lsum += pe;
        }
        lsum += __shfl_xor(lsum, 16);
        lsum += __shfl_xor(lsum, 32);
        l_run = l_run * alpha + lsum;
        m_run = m_new;
        #pragma unroll
        for (int r = 0; r < 4; r++) { o0[r] *= alpha; o1[r] *= alpha; }
        #pragma unroll
        for (int js = 0; js < 4; js++) {
            uint2 pk;
            pk.x = cvt_pk_bf16(p[js * 4 + 0], p[js * 4 + 1]);
            pk.y = cvt_pk_bf16(p[js * 4 + 2], p[js * 4 + 3]);
            *(uint2*)&P_lds[wave][lr][js * 16 + lg * 4] = pk;
        }
        #pragma unroll
        for (int ks = 0; ks < 2; ks++) {
            bfrag8 pb = *(const bfrag8*)&P_lds[wave][lr][ks * 32 + lg * 8];
            bfrag8 v0 = *(const bfrag8*)&vbt[(long)(h * HD + lr) * N + j0 + ks * 32 + lg * 8];
            bfrag8 v1 = *(const bfrag8*)&vbt[(long)(h * HD + 16 + lr) * N + j0 + ks * 32 + lg * 8];
            o0 = __builtin_amdgcn_mfma_f32_16x16x32_bf16(v0, pb, o0, 0, 0, 0);
            o1 = __builtin_amdgcn_mfma_f32_16x16x32_bf16(v1, pb, o1, 0, 0, 0);
        }
    }

    if (lg == 0) { mrg_m[wave][lr] = m_run; mrg_l[wave][lr] = l_run; }
    __syncthreads();
    int other = wave ^ 1;
    float m_o = mrg_m[other][lr], l_o = mrg_l[other][lr];
    float m_tot = fmaxf(m_run, m_o);
    float a_s = __expf(m_run - m_tot);
    float a_o = __expf(m_o - m_tot);
    float inv = 1.f / (a_s * l_run + a_o * l_o);
    if (jh == 0) {
        #pragma unroll
        for (int r = 0; r < 4; r++) {
            mrg_O[iw][lg * 4 + r][lr] = a_s * o0[r];
            mrg_O[iw][16 + lg * 4 + r][lr] = a_s * o1[r];
        }
    }
    __syncthreads();
    if (jh == 1) {
        #pragma unroll
        for (int r = 0; r < 4; r++) {
            float f0 = (mrg_O[iw][lg * 4 + r][lr] + a_s * o0[r]) * inv;
            float f1 = (mrg_O[iw][16 + lg * 4 + r][lr] + a_s * o1[r]) * inv;
            aob[(long)i * D + h * HD + lg * 4 + r] = f2bf(f0);
            aob[(long)i * D + h * HD + 16 + lg * 4 + r] = f2bf(f1);
        }
    }
}

// ---------------- edge MLP v3: LDS union + reg frags + hoisted MM2 reads + EF prefetch -
__global__ __launch_bounds__(256) void edge_mlp_mfma_kernel(
    const float* __restrict__ ef, const float* __restrict__ w1, const float* __restrict__ b1,
    const float* __restrict__ w2, const float* __restrict__ b2, float* __restrict__ ebT) {
    // union: first 8192 u16 stage w1t(4096)+w2t(4096); after frag load, reused as hid[4][16*264]
    __shared__ __align__(16) u16 smem[4][16 * 264];   // 33 KB
    u16* w1t = &smem[0][0];
    u16* w2t = w1t + 4096;
    int t = threadIdx.x;
    int i = blockIdx.x;

    {   // stage transposed bf16 weights
        int d = t;
        #pragma unroll
        for (int e = 0; e < 16; e++) w1t[d * 16 + e] = f2bf(w1[e * 256 + d]);
        float4 wa = *(const float4*)&w2[d * 8];
        float4 wb = *(const float4*)&w2[d * 8 + 4];
        w2t[0 * 256 + d] = f2bf(wa.x);
        w2t[1 * 256 + d] = f2bf(wa.y);
        w2t[2 * 256 + d] = f2bf(wa.z);
        w2t[3 * 256 + d] = f2bf(wa.w);
        w2t[4 * 256 + d] = f2bf(wb.x);
        w2t[5 * 256 + d] = f2bf(wb.y);
        w2t[6 * 256 + d] = f2bf(wb.z);
        w2t[7 * 256 + d] = f2bf(wb.w);
        #pragma unroll
        for (int h = 8; h < 16; h++) w2t[h * 256 + d] = 0;
    }
    __syncthreads();

    int wave = t >> 6, lane = t & 63;
    int lg = lane >> 4, lr = lane & 15;

    // A1/A2 fragments -> registers (weights; bias folded at k=16 of A1)
    bfrag8 a1[16];
    #pragma unroll
    for (int dt = 0; dt < 16; dt++) {
        int d = dt * 16 + lr;
        if (lg < 2) {
            a1[dt] = *(const bfrag8*)&w1t[d * 16 + lg * 8];
        } else if (lg == 2) {
            union { unsigned int u[4]; bfrag8 s; } z = {{0u, 0u, 0u, 0u}};
            z.u[0] = (unsigned int)f2bf(b1[d]);
            a1[dt] = z.s;
        } else {
            union { unsigned int u[4]; bfrag8 s; } z = {{0u, 0u, 0u, 0u}};
            a1[dt] = z.s;
        }
    }
    bfrag8 a2[8];
    #pragma unroll
    for (int ks = 0; ks < 8; ks++)
        a2[ks] = *(const bfrag8*)&w2t[lr * 256 + ks * 32 + lg * 8];

    float b2v[4];
    #pragma unroll
    for (int r = 0; r < 4; r++) b2v[r] = (lg < 2) ? b2[lg * 4 + r] : 0.f;

    __syncthreads();   // staging area now dead -> reuse as hid
    u16* hw = smem[wave];

    // prefetch first EF chunk
    float4 f0, f1;
    if (lg < 2) {
        const float* p = &ef[((long)i * N + wave * 16 + lr) * E + lg * 8];
        f0 = *(const float4*)p;
        f1 = *(const float4*)(p + 4);
    }

    for (int it = 0; it < 16; it++) {
        long rowbase = (long)i * N + (it * 4 + wave) * 16;
        // build B1-frag from prefetched EF (k=16 -> 1.0 bias slot for lg==2)
        bfrag8 bfrag;
        if (lg < 2) {
            union { unsigned int u[4]; bfrag8 s; } uu;
            uu.u[0] = cvt_pk_bf16(f0.x, f0.y);
            uu.u[1] = cvt_pk_bf16(f0.z, f0.w);
            uu.u[2] = cvt_pk_bf16(f1.x, f1.y);
            uu.u[3] = cvt_pk_bf16(f1.z, f1.w);
            bfrag = uu.s;
        } else {
            union { unsigned int u[4]; bfrag8 s; } uu = {{(lg == 2) ? 0x3f80u : 0u, 0u, 0u, 0u}};
            bfrag = uu.s;
        }
        // issue next EF load early (hides HBM latency under MM1+MM2)
        if (it < 15 && lg < 2) {
            const float* p = &ef[((long)i * N + ((it + 1) * 4 + wave) * 16 + lr) * E + lg * 8];
            f0 = *(const float4*)p;
            f1 = *(const float4*)(p + 4);
        }
        // MM1 (16 MFMAs) + silu + pack -> per-wave LDS hidden
        #pragma unroll
        for (int dt = 0; dt < 16; dt++) {
            accf4 acc = {0.f, 0.f, 0.f, 0.f};
            acc = __builtin_amdgcn_mfma_f32_16x16x32_bf16(a1[dt], bfrag, acc, 0, 0, 0);
            float s0 = silu_f(acc[0]);
            float s1 = silu_f(acc[1]);
            float s2 = silu_f(acc[2]);
            float s3 = silu_f(acc[3]);
            uint2 pk;
            pk.x = cvt_pk_bf16(s0, s1);
            pk.y = cvt_pk_bf16(s2, s3);
            *(uint2*)&hw[lr * 264 + dt * 16 + lg * 4] = pk;
        }
        // MM2: hoist ALL 8 LDS reads (independent), then dependent MFMA chain
        bfrag8 hbv[8];
        #pragma unroll
        for (int ks = 0; ks < 8; ks++)
            hbv[ks] = *(const bfrag8*)&hw[lr * 264 + ks * 32 + lg * 8];
        accf4 acc2 = {0.f, 0.f, 0.f, 0.f};
        #pragma unroll
        for (int ks = 0; ks < 8; ks++)
            acc2 = __builtin_amdgcn_mfma_f32_16x16x32_bf16(a2[ks], hbv[ks], acc2, 0, 0, 0);
        if (lg < 2) {
            #pragma unroll
            for (int r = 0; r < 4; r++)
                ebT[(long)(lg * 4 + r) * NN + rowbase + lr] = acc2[r] + b2v[r];
        }
    }
}

// =====================================================================================
extern "C" void kernel_launch(void* const* d_in, const int* in_sizes, int n_in,
                              void* d_out, int out_size, void* d_ws, size_t ws_size,
                              hipStream_t stream) {
    const float* features   = (const float*)d_in[0];
    const int*   adjacency  = (const int*)d_in[1];
    const float* edge_feats = (const float*)d_in[2];
    const int*   role_idx   = (const int*)d_in[3];
    const float* role_norm_w = (const float*)d_in[4];
    const float* role_q_w = (const float*)d_in[5];
    const float* role_k_w = (const float*)d_in[6];
    const float* role_v_w = (const float*)d_in[7];
    const float* role_o_w = (const float*)d_in[8];
    const float* nb_norm_w = (const float*)d_in[9];
    const float* nb_q_w = (const float*)d_in[10];
    const float* nb_k_w = (const float*)d_in[11];
    const float* nb_v_w = (const float*)d_in[12];
    const float* nb_o_w = (const float*)d_in[13];
    const float* edge_w1 = (const float*)d_in[14];
    const float* edge_b1 = (const float*)d_in[15];
    const float* edge_w2 = (const float*)d_in[16];
    const float* edge_b2 = (const float*)d_in[17];
    const float* full_norm_w = (const float*)d_in[18];
    const float* full_q_w = (const float*)d_in[19];
    const float* full_k_w = (const float*)d_in[20];
    const float* full_v_w = (const float*)d_in[21];
    const float* full_o_w = (const float*)d_in[22];
    const float* feat_norm_w = (const float*)d_in[23];
    const float* feat_t_w = (const float*)d_in[24];
    const float* feat_t_b = (const float*)d_in[25];
    const float* feat_g_w = (const float*)d_in[26];
    const float* feat_g_b = (const float*)d_in[27];
    const float* ffn_norm_w = (const float*)d_in[28];
    const float* ffn_gate_w = (const float*)d_in[29];
    const float* ffn_up_w = (const float*)d_in[30];
    const float* ffn_down_w = (const float*)d_in[31];

    // ---- workspace carve (256B aligned) ----
    char* wsp = (char*)d_ws;
    size_t off = 0;
    auto alloc = [&](size_t bytes) -> void* {
        void* p = wsp + off;
        off += (bytes + 255) & ~(size_t)255;
        return p;
    };
    float* x    = (float*)alloc((size_t)N * D * 4);
    float* tmp  = (float*)alloc((size_t)N * D * 4);      // gate pre-act
    float* eb   = (float*)alloc((size_t)H * NN * 4);     // ebT[h][i][j]
    u16* qkvbf = (u16*)alloc((size_t)N * 768 * 2);
    u16* guvb = (u16*)alloc((size_t)N * 2048 * 2);       // ffn gate|up bf16
    u16* aob  = (u16*)alloc((size_t)N * D * 2);
    u16* xnb  = (u16*)alloc((size_t)N * D * 2);
    u16* tb   = (u16*)alloc((size_t)N * D * 2);
    u16* hb   = (u16*)alloc((size_t)N * F * 2);
    u16* vbt  = (u16*)alloc((size_t)D * N * 2);
    u16* wall = (u16*)alloc((size_t)15 * 65536 * 2);     // 15 transposed 256x256 weights
    u16* wgut = (u16*)alloc((size_t)2048 * 256 * 2);
    u16* wdt  = (u16*)alloc((size_t)256 * 1024 * 2);

    // wall layout: per attn a: q,k,v at (a*4+0..2), o at (a*4+3); 12=feat_t,13=g1,14=g2
    u16* wqkvt[3], *wot[3];
    for (int a = 0; a < 3; a++) {
        wqkvt[a] = wall + (size_t)(a * 4) * 65536;
        wot[a]   = wall + (size_t)(a * 4 + 3) * 65536;
    }
    u16* wtt  = wall + (size_t)12 * 65536;
    u16* wg1t = wall + (size_t)13 * 65536;
    u16* wg2t = wall + (size_t)14 * 65536;

    // ---- batched weight transposes (3 launches) ----
    Src15 s15;
    s15.p[0] = role_q_w;  s15.p[1] = role_k_w;  s15.p[2] = role_v_w;  s15.p[3] = role_o_w;
    s15.p[4] = nb_q_w;    s15.p[5] = nb_k_w;    s15.p[6] = nb_v_w;    s15.p[7] = nb_o_w;
    s15.p[8] = full_q_w;  s15.p[9] = full_k_w;  s15.p[10] = full_v_w; s15.p[11] = full_o_w;
    s15.p[12] = feat_t_w; s15.p[13] = feat_g_w; s15.p[14] = feat_g_w + (size_t)D * D;
    transpose15_kernel<<<dim3(8, 8, 15), 256, 0, stream>>>(s15, wall);
    Src2 s2;
    s2.p[0] = ffn_gate_w; s2.p[1] = ffn_up_w;
    transpose_gu_kernel<<<dim3(32, 8, 2), 256, 0, stream>>>(s2, wgut);
    transpose_bf16_kernel<<<dim3(8, 32), 256, 0, stream>>>(ffn_down_w, D, wdt, F, D);

    // x = features; edge bias (transposed layout)
    copy4_kernel<<<(N * D / 4) / 256, 256, 0, stream>>>((const float4*)features, (float4*)x, N * D / 4);
    edge_mlp_mfma_kernel<<<N, 256, 0, stream>>>(edge_feats, edge_w1, edge_b1, edge_w2, edge_b2, eb);

    const float* nw[3] = {role_norm_w, nb_norm_w, full_norm_w};
    dim3 fgrid(N / 32, H);

    for (int a = 0; a < 3; a++) {
        rmsnorm_bf16_kernel<<<N, 256, 0, stream>>>(x, nw[a], xnb);
        // fused qkv projection -> bf16 directly
        bgemm_kernel<4, 0, false, false, true><<<dim3(768 / 64, N / 64, 1), 256, 0, stream>>>(
            xnb, wqkvt[a], nullptr, qkvbf, N, 256, 768, 768, 0, 0, 0);
        // V^T bf16 [256][1024] from qkvbf cols 512..767
        transpose_u16_kernel<<<dim3(8, 32), 256, 0, stream>>>(qkvbf + 512, 768, vbt, N, D);
        if (a == 0)
            flash_attn_kernel<1><<<fgrid, 256, 0, stream>>>(qkvbf, vbt, nullptr, role_idx, nullptr, aob);
        else if (a == 1)
            flash_attn_kernel<2><<<fgrid, 256, 0, stream>>>(qkvbf, vbt, eb, nullptr, adjacency, aob);
        else
            flash_attn_kernel<0><<<fgrid, 256, 0, stream>>>(qkvbf, vbt, nullptr, nullptr, nullptr, aob);
        // o-projection, accumulate into x
        bgemm_kernel<4, 0, true, false, false><<<dim3(D / 64, N / 64, 1), 256, 0, stream>>>(
            aob, wot[a], nullptr, x, N, 256, D, D, 0, 0, 0);
    }

    // ---- 4. feature mixing ----
    rmsnorm_bf16_kernel<<<N, 256, 0, stream>>>(x, feat_norm_w, xnb);
    bgemm_kernel<4, 1, false, true, true><<<dim3(D / 64, N / 64, 1), 256, 0, stream>>>(
        xnb, wtt, feat_t_b, tb, N, 256, D, D, 0, 0, 0);                    // tb = bf16(silu(xn@Wt+b))
    bgemm_kernel<4, 0, false, true, false><<<dim3(D / 64, N / 64, 1), 256, 0, stream>>>(
        xnb, wg1t, feat_g_b, tmp, N, 256, D, D, 0, 0, 0);                  // tmp = xn@G1+b
    bgemm_kernel<4, 0, true, false, false><<<dim3(D / 64, N / 64, 1), 256, 0, stream>>>(
        tb, wg2t, nullptr, tmp, N, 256, D, D, 0, 0, 0);                    // tmp += t@G2
    gate_combine_kernel<<<(N * D) / 256, 256, 0, stream>>>(tmp, tb, x, N * D);

    // ---- 5. gated FFN ----
    rmsnorm_bf16_kernel<<<N, 256, 0, stream>>>(x, ffn_norm_w, xnb);
    bgemm_kernel<4, 0, false, false, true><<<dim3(2048 / 64, N / 64, 1), 256, 0, stream>>>(
        xnb, wgut, nullptr, guvb, N, 256, 2048, 2048, 0, 0, 0);            // gate|up bf16
    ffn_mulcvt_kernel<<<(N * F) / 256, 256, 0, stream>>>(guvb, hb);
    bgemm_kernel<4, 0, true, false, false><<<dim3(D / 64, N / 64, 1), 256, 0, stream>>>(
        hb, wdt, nullptr, x, N, 1024, D, D, 0, 0, 0);                      // x += h@down
    copy4_kernel<<<(N * D / 4) / 256, 256, 0, stream>>>((const float4*)x, (float4*)d_out, N * D / 4);
}

// Round 13
// 481.262 us; speedup vs baseline: 2.9925x; 1.0211x over previous
//
#include <hip/hip_runtime.h>
#include <math.h>

#define N 1024
#define D 256
#define E 16
#define H 8
#define HD 32
#define F 1024
#define NN (1024 * 1024)
#define SCALE 0.17677669529663687f /* 1/sqrt(32) */
#define EPS 1e-6f

typedef unsigned short u16;
typedef __attribute__((ext_vector_type(8))) short bfrag8;
typedef __attribute__((ext_vector_type(4))) float accf4;

// ---------------- helpers ----------------
__device__ __forceinline__ float block_sum(float v) {
    #pragma unroll
    for (int off = 32; off > 0; off >>= 1) v += __shfl_xor(v, off);
    __shared__ float ws[4];
    if ((threadIdx.x & 63) == 0) ws[threadIdx.x >> 6] = v;
    __syncthreads();
    v = ws[0] + ws[1] + ws[2] + ws[3];
    __syncthreads();
    return v;
}

__device__ __forceinline__ float silu_f(float x) { return x / (1.f + __expf(-x)); }
__device__ __forceinline__ float sigmoid_f(float x) { return 1.f / (1.f + __expf(-x)); }

__device__ __forceinline__ u16 f2bf(float x) {
    union { float f; unsigned int u; } c;
    c.f = x;
    unsigned int r = c.u + 0x7fffu + ((c.u >> 16) & 1u);
    return (u16)(r >> 16);
}

__device__ __forceinline__ float bf2f(u16 v) {
    union { unsigned int u; float f; } c;
    c.u = ((unsigned int)v) << 16;
    return c.f;
}

__device__ __forceinline__ unsigned int cvt_pk_bf16(float a, float b) {
    unsigned int r;
    asm("v_cvt_pk_bf16_f32 %0, %1, %2" : "=v"(r) : "v"(a), "v"(b));
    return r;
}

// ---------------- rmsnorm -> bf16 (output row stride ldo) ----------------
__global__ void rmsnorm_bf16_kernel(const float* __restrict__ x, const float* __restrict__ w,
                                    u16* __restrict__ out, int ldo) {
    int row = blockIdx.x;
    int t = threadIdx.x;
    float v = x[(long)row * D + t];
    float s = block_sum(v * v);
    float rms = sqrtf(s * (1.f / D) + EPS);
    out[(long)row * ldo + t] = f2bf(v / rms * w[t]);
}

// ---------------- transposes ----------------
// generic: in fp32 [K][ldin] -> out bf16 [Nc][K]
__global__ void transpose_bf16_kernel(const float* __restrict__ in, long ldin,
                                      u16* __restrict__ out, int K, int Nc) {
    __shared__ float tile[32][33];
    int k0 = blockIdx.y * 32, n0 = blockIdx.x * 32;
    int c = threadIdx.x & 31, r8 = threadIdx.x >> 5;
    #pragma unroll
    for (int i = 0; i < 4; i++) {
        int r = r8 + i * 8;
        tile[r][c] = in[(long)(k0 + r) * ldin + n0 + c];
    }
    __syncthreads();
    #pragma unroll
    for (int i = 0; i < 4; i++) {
        int r = r8 + i * 8;
        out[(long)(n0 + r) * K + k0 + c] = f2bf(tile[c][r]);
    }
}

// batched 256x256 fp32->bf16 transposes (15 weights in one launch), dst contiguous
struct Src15 { const float* p[15]; };
__global__ void transpose15_kernel(Src15 srcs, u16* __restrict__ wall) {
    __shared__ float tile[32][33];
    const float* in = srcs.p[blockIdx.z];
    u16* out = wall + (size_t)blockIdx.z * 65536;
    int k0 = blockIdx.y * 32, n0 = blockIdx.x * 32;
    int c = threadIdx.x & 31, r8 = threadIdx.x >> 5;
    #pragma unroll
    for (int i = 0; i < 4; i++) {
        int r = r8 + i * 8;
        tile[r][c] = in[(long)(k0 + r) * 256 + n0 + c];
    }
    __syncthreads();
    #pragma unroll
    for (int i = 0; i < 4; i++) {
        int r = r8 + i * 8;
        out[(long)(n0 + r) * 256 + k0 + c] = f2bf(tile[c][r]);
    }
}

// gate/up [256][1024] -> bf16 interleaved rows: chunk c (f=32c..32c+31):
// rows 64c..64c+31 = gate f, rows 64c+32..64c+63 = up f.  z=0 gate, z=1 up.
struct Src2 { const float* p[2]; };
__global__ void transpose_gu_kernel(Src2 srcs, u16* __restrict__ wgut) {
    __shared__ float tile[32][33];
    const float* in = srcs.p[blockIdx.z];
    int zoff = blockIdx.z * 32;
    int k0 = blockIdx.y * 32, f0 = blockIdx.x * 32;
    int c = threadIdx.x & 31, r8 = threadIdx.x >> 5;
    #pragma unroll
    for (int i = 0; i < 4; i++) {
        int r = r8 + i * 8;
        tile[r][c] = in[(long)(k0 + r) * F + f0 + c];
    }
    __syncthreads();
    #pragma unroll
    for (int i = 0; i < 4; i++) {
        int r = r8 + i * 8;
        int rnew = (f0 >> 5) * 64 + zoff + r;
        wgut[(long)rnew * 256 + k0 + c] = f2bf(tile[c][r]);
    }
}

// u16 -> u16 transpose: in [K][ldin] -> out [Nc][K]
__global__ void transpose_u16_kernel(const u16* __restrict__ in, long ldin,
                                     u16* __restrict__ out, int K, int Nc) {
    __shared__ u16 tile[32][34];
    int k0 = blockIdx.y * 32, n0 = blockIdx.x * 32;
    int c = threadIdx.x & 31, r8 = threadIdx.x >> 5;
    #pragma unroll
    for (int i = 0; i < 4; i++) {
        int r = r8 + i * 8;
        tile[r][c] = in[(long)(k0 + r) * ldin + n0 + c];
    }
    __syncthreads();
    #pragma unroll
    for (int i = 0; i < 4; i++) {
        int r = r8 + i * 8;
        out[(long)(n0 + r) * K + k0 + c] = tile[c][r];
    }
}

// ---------------- bf16 MFMA GEMM ----------------
// C[M][ldc] (+)= act(A[M][lda] @ B^T[Nc][K] + bias); A,B bf16 (B pre-transposed).
// ACT: 0 none, 1 silu, 2 gate (sigmoid(v+b)*gt -> accum), 3 ffn-pair (silu(g)*u, NTW=4).
// SRC: Cf[idx] = csrc[idx] + v (fresh write from a different source buffer).
// A-frag: row=lane&15, k=(lane>>4)*8+j.  C: row=(lane>>4)*4+reg, col=lane&15 (HW-verified r6).
template <int NTW, int ACT, bool ACCUM, bool BIAS, bool BF16O, bool SRC>
__global__ __launch_bounds__(256) void bgemm_kernel(
    const u16* __restrict__ A, const u16* __restrict__ B, const float* __restrict__ bias,
    void* __restrict__ C, const float* __restrict__ csrc, const u16* __restrict__ gt, int ldg,
    int M, int K, int lda, int Nc, int ldc, long sA, long sB, long sC) {
    constexpr int NTILE = NTW * 16;
    __shared__ __align__(16) u16 Asm[64 * 72];
    __shared__ __align__(16) u16 Bsm[NTILE * 72];
    A += (long)blockIdx.z * sA;
    B += (long)blockIdx.z * sB;
    long cbase = (long)blockIdx.z * sC;
    int m0 = blockIdx.y * 64, n0 = blockIdx.x * NTILE;
    int t = threadIdx.x;
    int wave = t >> 6, lane = t & 63, lg = lane >> 4, lr = lane & 15;
    accf4 acc[NTW] = {};
    for (int k0 = 0; k0 < K; k0 += 64) {
        #pragma unroll
        for (int c = 0; c < 2; c++) {
            int flat = c * 4096 + t * 16;
            int row = flat >> 7, col = (flat & 127) >> 1;
            *(int4*)&Asm[row * 72 + col] = *(const int4*)&A[(long)(m0 + row) * lda + k0 + col];
        }
        #pragma unroll
        for (int c = 0; c < NTW / 2; c++) {
            int flat = c * 4096 + t * 16;
            int row = flat >> 7, col = (flat & 127) >> 1;
            *(int4*)&Bsm[row * 72 + col] = *(const int4*)&B[(long)(n0 + row) * K + k0 + col];
        }
        __syncthreads();
        #pragma unroll
        for (int ks = 0; ks < 2; ks++) {
            bfrag8 af = *(const bfrag8*)&Asm[(wave * 16 + lr) * 72 + ks * 32 + lg * 8];
            #pragma unroll
            for (int nt = 0; nt < NTW; nt++) {
                bfrag8 bf = *(const bfrag8*)&Bsm[(nt * 16 + lr) * 72 + ks * 32 + lg * 8];
                acc[nt] = __builtin_amdgcn_mfma_f32_16x16x32_bf16(af, bf, acc[nt], 0, 0, 0);
            }
        }
        __syncthreads();
    }
    float* Cf = (float*)C;
    u16* Cb = (u16*)C;
    if (ACT == 3) {
        // gate rows = local 0..31 (nt 0,1), up rows = local 32..63 (nt 2,3); f = n0/2 + nt*16+lr
        #pragma unroll
        for (int nt = 0; nt < 2; nt++) {
            int fcol = (n0 >> 1) + nt * 16 + lr;
            #pragma unroll
            for (int r = 0; r < 4; r++) {
                int gm = m0 + wave * 16 + lg * 4 + r;
                float g = acc[nt][r];
                float u = acc[nt + 2][r];
                Cb[(long)gm * ldc + fcol] = f2bf(silu_f(g) * u);
            }
        }
    } else {
        #pragma unroll
        for (int nt = 0; nt < NTW; nt++) {
            int gn = n0 + nt * 16 + lr;
            #pragma unroll
            for (int r = 0; r < 4; r++) {
                int gm = m0 + wave * 16 + lg * 4 + r;
                float v = acc[nt][r];
                if (BIAS) v += bias[gn];
                if (ACT == 1) v = silu_f(v);
                if (ACT == 2) v = sigmoid_f(v) * bf2f(gt[(long)gm * ldg + gn]);
                long idx = cbase + (long)gm * ldc + gn;
                if (BF16O) Cb[idx] = f2bf(v);
                else if (SRC) Cf[idx] = csrc[idx] + v;
                else if (ACCUM) Cf[idx] += v;
                else Cf[idx] = v;
            }
        }
    }
}

// ---------------- fused flash attention (HW-validated r8; ebT now bf16) ----------
template <int MASK>
__global__ __launch_bounds__(256) void flash_attn_kernel(
    const u16* __restrict__ qkvbf, const u16* __restrict__ vbt,
    const u16* __restrict__ ebTb, const int* __restrict__ roles,
    const int* __restrict__ adj, u16* __restrict__ aob) {
    __shared__ int roles_s[N];
    __shared__ __align__(16) u16 P_lds[4][16][72];
    __shared__ float mrg_m[4][16], mrg_l[4][16];
    __shared__ __align__(16) float mrg_O[2][32][16];

    int h = blockIdx.y;
    int t = threadIdx.x, wave = t >> 6, lane = t & 63;
    int lg = lane >> 4, lr = lane & 15;
    int iw = wave >> 1, jh = wave & 1;
    int i = blockIdx.x * 32 + iw * 16 + lr;

    if (MASK == 1) {
        #pragma unroll
        for (int c = 0; c < 4; c++) roles_s[t + c * 256] = roles[t + c * 256];
    }
    __syncthreads();

    bfrag8 qf = *(const bfrag8*)&qkvbf[(long)i * 768 + h * HD + lg * 8];
    int role_i = (MASK == 1) ? roles_s[i] : 0;

    accf4 o0 = {0.f, 0.f, 0.f, 0.f}, o1 = {0.f, 0.f, 0.f, 0.f};
    float m_run = -1e30f, l_run = 0.f;

    for (int jt = 0; jt < 8; jt++) {
        int j0 = jh * 512 + jt * 64;
        float p[16];
        float tmax = -1e30f;
        #pragma unroll
        for (int js = 0; js < 4; js++) {
            bfrag8 kf = *(const bfrag8*)&qkvbf[(long)(j0 + js * 16 + lr) * 768 + 256 + h * HD + lg * 8];
            accf4 z = {0.f, 0.f, 0.f, 0.f};
            accf4 s = __builtin_amdgcn_mfma_f32_16x16x32_bf16(kf, qf, z, 0, 0, 0);
            uint2 e2;
            int4 ad4;
            if (MASK == 2) {
                e2 = *(const uint2*)&ebTb[(long)h * NN + (long)i * N + j0 + js * 16 + lg * 4];
                ad4 = *(const int4*)&adj[(long)i * N + j0 + js * 16 + lg * 4];
            }
            #pragma unroll
            for (int r = 0; r < 4; r++) {
                int j = j0 + js * 16 + lg * 4 + r;
                float val = s[r] * SCALE;
                bool keep = true;
                if (MASK == 2) {
                    unsigned int w = (r < 2) ? e2.x : e2.y;
                    val += bf2f((u16)(w >> ((r & 1) * 16)));
                    int av = (r == 0) ? ad4.x : (r == 1) ? ad4.y : (r == 2) ? ad4.z : ad4.w;
                    keep = (av > 0) || (i == j);
                }
                if (MASK == 1) keep = (roles_s[j] == role_i);
                val = keep ? val : -1e30f;
                p[js * 4 + r] = val;
                tmax = fmaxf(tmax, val);
            }
        }
        tmax = fmaxf(tmax, __shfl_xor(tmax, 16));
        tmax = fmaxf(tmax, __shfl_xor(tmax, 32));
        float m_new = fmaxf(m_run, tmax);
        float alpha = __expf(m_run - m_new);
        float lsum = 0.f;
        #pragma unroll
        for (int v = 0; v < 16; v++) {
            float pe = __expf(p[v] - m_new);
            p[v] = pe;
            lsum += pe;
        }
        lsum += __shfl_xor(lsum, 16);
        lsum += __shfl_xor(lsum, 32);
        l_run = l_run * alpha + lsum;
        m_run = m_new;
        #pragma unroll
        for (int r = 0; r < 4; r++) { o0[r] *= alpha; o1[r] *= alpha; }
        #pragma unroll
        for (int js = 0; js < 4; js++) {
            uint2 pk;
            pk.x = cvt_pk_bf16(p[js * 4 + 0], p[js * 4 + 1]);
            pk.y = cvt_pk_bf16(p[js * 4 + 2], p[js * 4 + 3]);
            *(uint2*)&P_lds[wave][lr][js * 16 + lg * 4] = pk;
        }
        #pragma unroll
        for (int ks = 0; ks < 2; ks++) {
            bfrag8 pb = *(const bfrag8*)&P_lds[wave][lr][ks * 32 + lg * 8];
            bfrag8 v0 = *(const bfrag8*)&vbt[(long)(h * HD + lr) * N + j0 + ks * 32 + lg * 8];
            bfrag8 v1 = *(const bfrag8*)&vbt[(long)(h * HD + 16 + lr) * N + j0 + ks * 32 + lg * 8];
            o0 = __builtin_amdgcn_mfma_f32_16x16x32_bf16(v0, pb, o0, 0, 0, 0);
            o1 = __builtin_amdgcn_mfma_f32_16x16x32_bf16(v1, pb, o1, 0, 0, 0);
        }
    }

    if (lg == 0) { mrg_m[wave][lr] = m_run; mrg_l[wave][lr] = l_run; }
    __syncthreads();
    int other = wave ^ 1;
    float m_o = mrg_m[other][lr], l_o = mrg_l[other][lr];
    float m_tot = fmaxf(m_run, m_o);
    float a_s = __expf(m_run - m_tot);
    float a_o = __expf(m_o - m_tot);
    float inv = 1.f / (a_s * l_run + a_o * l_o);
    if (jh == 0) {
        #pragma unroll
        for (int r = 0; r < 4; r++) {
            mrg_O[iw][lg * 4 + r][lr] = a_s * o0[r];
            mrg_O[iw][16 + lg * 4 + r][lr] = a_s * o1[r];
        }
    }
    __syncthreads();
    if (jh == 1) {
        #pragma unroll
        for (int r = 0; r < 4; r++) {
            float f0 = (mrg_O[iw][lg * 4 + r][lr] + a_s * o0[r]) * inv;
            float f1 = (mrg_O[iw][16 + lg * 4 + r][lr] + a_s * o1[r]) * inv;
            aob[(long)i * D + h * HD + lg * 4 + r] = f2bf(f0);
            aob[(long)i * D + h * HD + 16 + lg * 4 + r] = f2bf(f1);
        }
    }
}

// ---------------- edge MLP v3 (output ebT bf16) ----------------
__global__ __launch_bounds__(256) void edge_mlp_mfma_kernel(
    const float* __restrict__ ef, const float* __restrict__ w1, const float* __restrict__ b1,
    const float* __restrict__ w2, const float* __restrict__ b2, u16* __restrict__ ebTb) {
    __shared__ __align__(16) u16 smem[4][16 * 264];   // 33 KB; staging union
    u16* w1t = &smem[0][0];
    u16* w2t = w1t + 4096;
    int t = threadIdx.x;
    int i = blockIdx.x;

    {   // stage transposed bf16 weights
        int d = t;
        #pragma unroll
        for (int e = 0; e < 16; e++) w1t[d * 16 + e] = f2bf(w1[e * 256 + d]);
        float4 wa = *(const float4*)&w2[d * 8];
        float4 wb = *(const float4*)&w2[d * 8 + 4];
        w2t[0 * 256 + d] = f2bf(wa.x);
        w2t[1 * 256 + d] = f2bf(wa.y);
        w2t[2 * 256 + d] = f2bf(wa.z);
        w2t[3 * 256 + d] = f2bf(wa.w);
        w2t[4 * 256 + d] = f2bf(wb.x);
        w2t[5 * 256 + d] = f2bf(wb.y);
        w2t[6 * 256 + d] = f2bf(wb.z);
        w2t[7 * 256 + d] = f2bf(wb.w);
        #pragma unroll
        for (int h = 8; h < 16; h++) w2t[h * 256 + d] = 0;
    }
    __syncthreads();

    int wave = t >> 6, lane = t & 63;
    int lg = lane >> 4, lr = lane & 15;

    bfrag8 a1[16];
    #pragma unroll
    for (int dt = 0; dt < 16; dt++) {
        int d = dt * 16 + lr;
        if (lg < 2) {
            a1[dt] = *(const bfrag8*)&w1t[d * 16 + lg * 8];
        } else if (lg == 2) {
            union { unsigned int u[4]; bfrag8 s; } z = {{0u, 0u, 0u, 0u}};
            z.u[0] = (unsigned int)f2bf(b1[d]);
            a1[dt] = z.s;
        } else {
            union { unsigned int u[4]; bfrag8 s; } z = {{0u, 0u, 0u, 0u}};
            a1[dt] = z.s;
        }
    }
    bfrag8 a2[8];
    #pragma unroll
    for (int ks = 0; ks < 8; ks++)
        a2[ks] = *(const bfrag8*)&w2t[lr * 256 + ks * 32 + lg * 8];

    float b2v[4];
    #pragma unroll
    for (int r = 0; r < 4; r++) b2v[r] = (lg < 2) ? b2[lg * 4 + r] : 0.f;

    __syncthreads();   // staging area now dead -> reuse as hid
    u16* hw = smem[wave];

    float4 f0, f1;
    if (lg < 2) {
        const float* p = &ef[((long)i * N + wave * 16 + lr) * E + lg * 8];
        f0 = *(const float4*)p;
        f1 = *(const float4*)(p + 4);
    }

    for (int it = 0; it < 16; it++) {
        long rowbase = (long)i * N + (it * 4 + wave) * 16;
        bfrag8 bfrag;
        if (lg < 2) {
            union { unsigned int u[4]; bfrag8 s; } uu;
            uu.u[0] = cvt_pk_bf16(f0.x, f0.y);
            uu.u[1] = cvt_pk_bf16(f0.z, f0.w);
            uu.u[2] = cvt_pk_bf16(f1.x, f1.y);
            uu.u[3] = cvt_pk_bf16(f1.z, f1.w);
            bfrag = uu.s;
        } else {
            union { unsigned int u[4]; bfrag8 s; } uu = {{(lg == 2) ? 0x3f80u : 0u, 0u, 0u, 0u}};
            bfrag = uu.s;
        }
        if (it < 15 && lg < 2) {
            const float* p = &ef[((long)i * N + ((it + 1) * 4 + wave) * 16 + lr) * E + lg * 8];
            f0 = *(const float4*)p;
            f1 = *(const float4*)(p + 4);
        }
        #pragma unroll
        for (int dt = 0; dt < 16; dt++) {
            accf4 acc = {0.f, 0.f, 0.f, 0.f};
            acc = __builtin_amdgcn_mfma_f32_16x16x32_bf16(a1[dt], bfrag, acc, 0, 0, 0);
            float s0 = silu_f(acc[0]);
            float s1 = silu_f(acc[1]);
            float s2 = silu_f(acc[2]);
            float s3 = silu_f(acc[3]);
            uint2 pk;
            pk.x = cvt_pk_bf16(s0, s1);
            pk.y = cvt_pk_bf16(s2, s3);
            *(uint2*)&hw[lr * 264 + dt * 16 + lg * 4] = pk;
        }
        bfrag8 hbv[8];
        #pragma unroll
        for (int ks = 0; ks < 8; ks++)
            hbv[ks] = *(const bfrag8*)&hw[lr * 264 + ks * 32 + lg * 8];
        accf4 acc2 = {0.f, 0.f, 0.f, 0.f};
        #pragma unroll
        for (int ks = 0; ks < 8; ks++)
            acc2 = __builtin_amdgcn_mfma_f32_16x16x32_bf16(a2[ks], hbv[ks], acc2, 0, 0, 0);
        if (lg < 2) {
            #pragma unroll
            for (int r = 0; r < 4; r++)
                ebTb[(long)(lg * 4 + r) * NN + rowbase + lr] = f2bf(acc2[r] + b2v[r]);
        }
    }
}

// =====================================================================================
extern "C" void kernel_launch(void* const* d_in, const int* in_sizes, int n_in,
                              void* d_out, int out_size, void* d_ws, size_t ws_size,
                              hipStream_t stream) {
    const float* features   = (const float*)d_in[0];
    const int*   adjacency  = (const int*)d_in[1];
    const float* edge_feats = (const float*)d_in[2];
    const int*   role_idx   = (const int*)d_in[3];
    const float* role_norm_w = (const float*)d_in[4];
    const float* role_q_w = (const float*)d_in[5];
    const float* role_k_w = (const float*)d_in[6];
    const float* role_v_w = (const float*)d_in[7];
    const float* role_o_w = (const float*)d_in[8];
    const float* nb_norm_w = (const float*)d_in[9];
    const float* nb_q_w = (const float*)d_in[10];
    const float* nb_k_w = (const float*)d_in[11];
    const float* nb_v_w = (const float*)d_in[12];
    const float* nb_o_w = (const float*)d_in[13];
    const float* edge_w1 = (const float*)d_in[14];
    const float* edge_b1 = (const float*)d_in[15];
    const float* edge_w2 = (const float*)d_in[16];
    const float* edge_b2 = (const float*)d_in[17];
    const float* full_norm_w = (const float*)d_in[18];
    const float* full_q_w = (const float*)d_in[19];
    const float* full_k_w = (const float*)d_in[20];
    const float* full_v_w = (const float*)d_in[21];
    const float* full_o_w = (const float*)d_in[22];
    const float* feat_norm_w = (const float*)d_in[23];
    const float* feat_t_w = (const float*)d_in[24];
    const float* feat_t_b = (const float*)d_in[25];
    const float* feat_g_w = (const float*)d_in[26];
    const float* feat_g_b = (const float*)d_in[27];
    const float* ffn_norm_w = (const float*)d_in[28];
    const float* ffn_gate_w = (const float*)d_in[29];
    const float* ffn_up_w = (const float*)d_in[30];
    const float* ffn_down_w = (const float*)d_in[31];

    // ---- workspace carve (256B aligned) ----
    char* wsp = (char*)d_ws;
    size_t off = 0;
    auto alloc = [&](size_t bytes) -> void* {
        void* p = wsp + off;
        off += (bytes + 255) & ~(size_t)255;
        return p;
    };
    float* x    = (float*)alloc((size_t)N * D * 4);
    u16* ebb  = (u16*)alloc((size_t)H * NN * 2);         // ebT[h][i][j] bf16
    u16* qkvbf = (u16*)alloc((size_t)N * 768 * 2);
    u16* aob  = (u16*)alloc((size_t)N * D * 2);
    u16* xnb  = (u16*)alloc((size_t)N * D * 2);
    u16* xnt  = (u16*)alloc((size_t)N * 512 * 2);        // [xn | t] concat, ld 512
    u16* hb   = (u16*)alloc((size_t)N * F * 2);
    u16* vbt  = (u16*)alloc((size_t)D * N * 2);
    u16* wall = (u16*)alloc((size_t)15 * 65536 * 2);     // 12 attn + feat_t
    u16* wgt  = (u16*)alloc((size_t)256 * 512 * 2);      // feat_g^T [256][512]
    u16* wgut = (u16*)alloc((size_t)2048 * 256 * 2);     // interleaved gate|up
    u16* wdt  = (u16*)alloc((size_t)256 * 1024 * 2);

    // wall layout: per attn a: q,k,v at (a*4+0..2), o at (a*4+3); 12 = feat_t
    u16* wqkvt[3], *wot[3];
    for (int a = 0; a < 3; a++) {
        wqkvt[a] = wall + (size_t)(a * 4) * 65536;
        wot[a]   = wall + (size_t)(a * 4 + 3) * 65536;
    }
    u16* wtt = wall + (size_t)12 * 65536;

    // ---- weight transposes (4 launches) ----
    Src15 s15;
    s15.p[0] = role_q_w;  s15.p[1] = role_k_w;  s15.p[2] = role_v_w;  s15.p[3] = role_o_w;
    s15.p[4] = nb_q_w;    s15.p[5] = nb_k_w;    s15.p[6] = nb_v_w;    s15.p[7] = nb_o_w;
    s15.p[8] = full_q_w;  s15.p[9] = full_k_w;  s15.p[10] = full_v_w; s15.p[11] = full_o_w;
    s15.p[12] = feat_t_w; s15.p[13] = feat_t_w; s15.p[14] = feat_t_w;  // 13,14 unused dup
    transpose15_kernel<<<dim3(8, 8, 13), 256, 0, stream>>>(s15, wall);
    transpose_bf16_kernel<<<dim3(8, 16), 256, 0, stream>>>(feat_g_w, D, wgt, 512, D); // [512][256]->[256][512]
    Src2 s2;
    s2.p[0] = ffn_gate_w; s2.p[1] = ffn_up_w;
    transpose_gu_kernel<<<dim3(32, 8, 2), 256, 0, stream>>>(s2, wgut);
    transpose_bf16_kernel<<<dim3(8, 32), 256, 0, stream>>>(ffn_down_w, D, wdt, F, D);

    // edge bias (bf16, transposed layout)
    edge_mlp_mfma_kernel<<<N, 256, 0, stream>>>(edge_feats, edge_w1, edge_b1, edge_w2, edge_b2, ebb);

    const float* nw[3] = {role_norm_w, nb_norm_w, full_norm_w};
    const float* xsrc0 = features;   // a=0 reads features as residual source
    dim3 fgrid(N / 32, H);

    for (int a = 0; a < 3; a++) {
        rmsnorm_bf16_kernel<<<N, 256, 0, stream>>>(a == 0 ? features : x, nw[a], xnb, 256);
        // fused qkv projection -> bf16
        bgemm_kernel<4, 0, false, false, true, false><<<dim3(768 / 64, N / 64, 1), 256, 0, stream>>>(
            xnb, wqkvt[a], nullptr, qkvbf, nullptr, nullptr, 0, N, 256, 256, 768, 768, 0, 0, 0);
        transpose_u16_kernel<<<dim3(8, 32), 256, 0, stream>>>(qkvbf + 512, 768, vbt, N, D);
        if (a == 0)
            flash_attn_kernel<1><<<fgrid, 256, 0, stream>>>(qkvbf, vbt, nullptr, role_idx, nullptr, aob);
        else if (a == 1)
            flash_attn_kernel<2><<<fgrid, 256, 0, stream>>>(qkvbf, vbt, ebb, nullptr, adjacency, aob);
        else
            flash_attn_kernel<0><<<fgrid, 256, 0, stream>>>(qkvbf, vbt, nullptr, nullptr, nullptr, aob);
        // o-projection: a=0 writes x = features + attn; a>0 accumulates into x
        if (a == 0)
            bgemm_kernel<4, 0, false, false, false, true><<<dim3(D / 64, N / 64, 1), 256, 0, stream>>>(
                aob, wot[a], nullptr, x, xsrc0, nullptr, 0, N, 256, 256, D, D, 0, 0, 0);
        else
            bgemm_kernel<4, 0, true, false, false, false><<<dim3(D / 64, N / 64, 1), 256, 0, stream>>>(
                aob, wot[a], nullptr, x, nullptr, nullptr, 0, N, 256, 256, D, D, 0, 0, 0);
    }

    // ---- 4. feature mixing (fused gate) ----
    rmsnorm_bf16_kernel<<<N, 256, 0, stream>>>(x, feat_norm_w, xnt, 512);         // xn -> left half
    bgemm_kernel<4, 1, false, true, true, false><<<dim3(D / 64, N / 64, 1), 256, 0, stream>>>(
        xnt, wtt, feat_t_b, xnt + 256, nullptr, nullptr, 0, N, 256, 512, D, 512, 0, 0, 0); // t -> right half
    // x += sigmoid(concat(xn,t) @ G + gb) * t     (one K=512 bgemm)
    bgemm_kernel<4, 2, true, true, false, false><<<dim3(D / 64, N / 64, 1), 256, 0, stream>>>(
        xnt, wgt, feat_g_b, x, nullptr, xnt + 256, 512, N, 512, 512, D, D, 0, 0, 0);

    // ---- 5. gated FFN (fused gate|up) ----
    rmsnorm_bf16_kernel<<<N, 256, 0, stream>>>(x, ffn_norm_w, xnb, 256);
    bgemm_kernel<4, 3, false, false, true, false><<<dim3(2048 / 64, N / 64, 1), 256, 0, stream>>>(
        xnb, wgut, nullptr, hb, nullptr, nullptr, 0, N, 256, 256, 2048, F, 0, 0, 0);  // hb = silu(g)*u bf16
    // d_out = x + hb @ down
    bgemm_kernel<4, 0, false, false, false, true><<<dim3(D / 64, N / 64, 1), 256, 0, stream>>>(
        hb, wdt, nullptr, d_out, x, nullptr, 0, N, 1024, 1024, D, D, 0, 0, 0);
}